// Round 7
// baseline (1014.264 us; speedup 1.0000x reference)
//
#include <hip/hip_runtime.h>
#include <stdint.h>

#define DEV __device__ __forceinline__

typedef uint16_t u16;
typedef __bf16 bf16x8 __attribute__((ext_vector_type(8)));
typedef float f32x4 __attribute__((ext_vector_type(4)));
typedef u16 u16x8 __attribute__((ext_vector_type(8)));

DEV float bf2f(u16 v) { return __uint_as_float(((uint32_t)v) << 16); }
DEV u16 f2bf(float f) {
  uint32_t u = __float_as_uint(f);
  u += 0x7fffu + ((u >> 16) & 1u);
  return (u16)(u >> 16);
}
DEV float gelu_f(float x) { return 0.5f * x * (1.0f + erff(x * 0.7071067811865475f)); }

DEV void gload_lds16(const u16* g, u16* l) {
  __builtin_amdgcn_global_load_lds(
      (const __attribute__((address_space(1))) void*)g,
      (__attribute__((address_space(3))) void*)l, 16, 0, 0);
}

// ---- all scratch in a static device global (R4: never trust ws_size) ----
struct __align__(16) Scratch {
  float POSb[64 * 512];
  float meanv[1024];
  float stdv[1024];
  int idxB[8192];
  float gatel[65536 * 2];
  float bqkv[1536];
  u16 gmeanB[1024 * 1024];
  u16 WqkvT[1536 * 512];       // rows 0-511 Wq^T, 512-1023 Wk^T, 1024-1535 Wv^T
  u16 WoT[512 * 512];
  u16 Wm1T[1024 * 512];
  u16 Wm2T[512 * 1024];
  u16 Wg1T[512 * 1024];
  u16 WhT[256 * 32768];        // rows 192..255 zero-filled
  u16 memdupB[8192 * 1536];    // [mh|mh|ml] 24 MB
  u16 embh[65536 * 512];       // 64 MB: emb -> mem (memc result, feeds mh)
  u16 locglob[65536 * 1024];   // 128 MB: [local | glob] contiguous rows
  u16 obuf[65536 * 512];       // 64 MB: hmean f32 slices (8MB) -> attention O
  u16 qkvb[65536 * 1536];      // 192 MB: Q|K|V (sim aliases + mh slices live here)
};
__device__ Scratch g_s;

// ================= merged setup kernel (block-range dispatch) =================
// [0,64) pos | [64,80) stats | [80,592) zero gatel | [592,1616) zero WhT pad |
// [1616,1622) biasqkv | [1622,10326) 8 transposes | [10326,12374) memdup
__global__ __launch_bounds__(256) void prep_kernel(const float* __restrict__ x_enc,
                                                   const float* __restrict__ bq,
                                                   const float* __restrict__ bk,
                                                   const float* __restrict__ bv,
                                                   const float* __restrict__ W_q,
                                                   const float* __restrict__ W_k,
                                                   const float* __restrict__ W_v,
                                                   const float* __restrict__ W_o,
                                                   const float* __restrict__ W_m1,
                                                   const float* __restrict__ W_m2,
                                                   const float* __restrict__ W_g1,
                                                   const float* __restrict__ W_h,
                                                   const float* __restrict__ mem_bank) {
  Scratch* S = &g_s;
  const int id = blockIdx.x;
  const int tid = threadIdx.x;
  __shared__ u16 tsh[32][33];
  __shared__ float sh[2][4][64];

  if (id < 64) {
    // POS embedding
    int n = id, i = tid;
    float div = expf((float)(2 * i) * (-9.210340371976184f / 512.0f));
    float arg = (float)n * div;
    S->POSb[n * 512 + 2 * i] = sinf(arg);
    S->POSb[n * 512 + 2 * i + 1] = cosf(arg);
  } else if (id < 80) {
    // instance-norm stats
    int b = id - 64;
    int v = tid & 63, g = tid >> 6;
    float s = 0.f, s2 = 0.f;
    for (int l = g; l < 512; l += 4) {
      float x = x_enc[((long)b * 512 + l) * 64 + v];
      s += x; s2 += x * x;
    }
    sh[0][g][v] = s; sh[1][g][v] = s2;
    __syncthreads();
    if (g == 0) {
      s = sh[0][0][v] + sh[0][1][v] + sh[0][2][v] + sh[0][3][v];
      s2 = sh[1][0][v] + sh[1][1][v] + sh[1][2][v] + sh[1][3][v];
      float mu = s * (1.f / 512.f);
      float var = s2 * (1.f / 512.f) - mu * mu;
      S->meanv[b * 64 + v] = mu;
      S->stdv[b * 64 + v] = sqrtf(var + 1e-5f) * 2.5f;  // sqrt(var+eps)/0.4
    }
  } else if (id < 592) {
    int t = (id - 80) * 256 + tid;  // < 131072
    S->gatel[t] = 0.f;
  } else if (id < 1616) {
    int t = (id - 592) * 256 + tid;  // < 262144
    *(u16x8*)(S->WhT + (size_t)192 * 32768 + (long)t * 8) = (u16x8)0;
  } else if (id < 1622) {
    int t = (id - 1616) * 256 + tid;  // < 1536
    S->bqkv[t] = t < 512 ? bq[t] : (t < 1024 ? bk[t - 512] : bv[t - 1024]);
  } else if (id < 10326) {
    // transposes: f32 [R,C] -> bf16 [C,R]
    int i = id - 1622;
    const float* tin; u16* tout; int R, C, bx, by;
    if (i < 256)       { tin = W_q;  tout = S->WqkvT;             R = 512;   C = 512;  bx = (i & 15) * 32; by = (i >> 4) * 32; }
    else if (i < 512)  { i -= 256;  tin = W_k;  tout = S->WqkvT + 512 * 512;     R = 512;   C = 512;  bx = (i & 15) * 32; by = (i >> 4) * 32; }
    else if (i < 768)  { i -= 512;  tin = W_v;  tout = S->WqkvT + 2 * 512 * 512; R = 512;   C = 512;  bx = (i & 15) * 32; by = (i >> 4) * 32; }
    else if (i < 1024) { i -= 768;  tin = W_o;  tout = S->WoT;    R = 512;   C = 512;  bx = (i & 15) * 32; by = (i >> 4) * 32; }
    else if (i < 1536) { i -= 1024; tin = W_m1; tout = S->Wm1T;   R = 512;   C = 1024; bx = (i & 31) * 32; by = (i >> 5) * 32; }
    else if (i < 2048) { i -= 1536; tin = W_m2; tout = S->Wm2T;   R = 1024;  C = 512;  bx = (i & 15) * 32; by = (i >> 4) * 32; }
    else if (i < 2560) { i -= 2048; tin = W_g1; tout = S->Wg1T;   R = 1024;  C = 512;  bx = (i & 15) * 32; by = (i >> 4) * 32; }
    else               { i -= 2560; tin = W_h;  tout = S->WhT;    R = 32768; C = 192;  bx = (i % 6) * 32;  by = (i / 6) * 32; }
    int tx = tid & 31, ty = tid >> 5;
    for (int r = ty; r < 32; r += 8) tsh[r][tx] = f2bf(tin[(long)(by + r) * C + bx + tx]);
    __syncthreads();
    for (int r = ty; r < 32; r += 8) tout[(long)(bx + r) * R + by + tx] = tsh[tx][r];
  } else {
    // mem_bank f32 -> [mh|mh|ml] bf16 row of 1536
    int t = (id - 10326) * 256 + tid;  // < 524288
    int n = t >> 6, k8 = (t & 63) * 8;
    const float* src = mem_bank + (long)n * 512 + k8;
    u16x8 hi, lo;
#pragma unroll
    for (int z = 0; z < 8; ++z) {
      float m = src[z];
      u16 h = f2bf(m);
      hi[z] = h;
      lo[z] = f2bf(m - bf2f(h));
    }
    long base = (long)n * 1536 + k8;
    *(u16x8*)(S->memdupB + base) = hi;
    *(u16x8*)(S->memdupB + base + 512) = hi;
    *(u16x8*)(S->memdupB + base + 1024) = lo;
  }
}

// ---------------- patch embed + fused qflat->[qh|ql|qh] row ----------------
__global__ __launch_bounds__(256) void emb_kernel(const float* __restrict__ x_enc,
                                                  const float* __restrict__ W_val,
                                                  const float* __restrict__ POS,
                                                  const float* __restrict__ meanv,
                                                  const float* __restrict__ stdv,
                                                  u16* __restrict__ embh,
                                                  u16* __restrict__ qsC) {
  int bn = blockIdx.x;
  int b = bn >> 6, v = bn & 63;
  int tid = threadIdx.x;
  __shared__ __align__(16) float wv[16 * 512];
  __shared__ __align__(16) float pt[64 * 16];
  for (int i = tid; i < 8192; i += 256) wv[i] = W_val[i];
  float mu = meanv[bn];
  float inv = 1.f / stdv[bn];
  for (int i = tid; i < 1024; i += 256) {
    int n = i >> 4, p = i & 15;
    int l = n * 8 + p; if (l > 511) l = 511;  // replication pad
    pt[i] = (x_enc[((long)b * 512 + l) * 64 + v] - mu) * inv;
  }
  __syncthreads();
  float qs0 = 0.f, qs1 = 0.f;
  int d0 = tid, d1 = tid + 256;
  for (int n = 0; n < 64; ++n) {
    float a0 = POS[n * 512 + d0], a1 = POS[n * 512 + d1];
#pragma unroll
    for (int p = 0; p < 16; ++p) {
      float pv = pt[n * 16 + p];
      a0 += pv * wv[p * 512 + d0];
      a1 += pv * wv[p * 512 + d1];
    }
    long base = ((long)bn * 64 + n) * 512;
    embh[base + d0] = f2bf(a0);
    embh[base + d1] = f2bf(a1);
    qs0 += a0; qs1 += a1;
  }
  float q0 = qs0 * (1.f / 64.f), q1 = qs1 * (1.f / 64.f);
  u16 h0 = f2bf(q0), l0 = f2bf(q0 - bf2f(h0));
  u16 h1 = f2bf(q1), l1 = f2bf(q1 - bf2f(h1));
  long qb = (long)bn * 1536;
  qsC[qb + d0] = h0; qsC[qb + 512 + d0] = l0; qsC[qb + 1024 + d0] = h0;
  qsC[qb + d1] = h1; qsC[qb + 512 + d1] = l1; qsC[qb + 1024 + d1] = h1;
}

// ---------------- double-buffered NT GEMM (T3 minimum 2-phase, counted vmcnt) -----
// EPI: 0 bias+bf16 | 1 bias+gelu+bf16 | 3 f32 store (z-sliced via zstride)
//      4 fused gate-logit epilogue (h1=gelu(acc+b); dot W_g2 -> atomics)
// blockIdx.z selects the K-slice (koff) AND the output slice (EPI 3).
template <int EPI>
__global__ __launch_bounds__(256) void gemm_db(const u16* __restrict__ Ag,
                                               const u16* __restrict__ Bt,
                                               const float* __restrict__ bias,
                                               void* __restrict__ C,
                                               const float* __restrict__ W_g2,
                                               float* __restrict__ gatel,
                                               int lda, int ldb, int K, int Nreal, int ldc,
                                               int nT, long zstride) {
  __shared__ __align__(16) u16 smem[4 * 128 * 64];  // 64 KB: 2 x (As 16K + Bs 16K)
  const int tid = threadIdx.x;
  const int id = blockIdx.x;
  const int xcd = id & 7;
  const int kk = id >> 3;
  const long bm = (long)((kk / nT) * 8 + xcd) * 128;
  const long bnn = (long)(kk % nT) * 128;
  const long koff = (long)blockIdx.z * (long)K;
  const int lane = tid & 63;
  const int w = tid >> 6;
  const int wm = (w & 1) * 64;
  const int wn = (w >> 1) * 64;
  const int r16 = lane & 15;
  const int q4 = lane >> 4;

  f32x4 acc[4][4] = {};

  const u16* ap[4];
  const u16* bp[4];
  int ao[4], bo[4];
#pragma unroll
  for (int j = 0; j < 4; ++j) {
    int cid = (j * 4 + w) * 64 + lane;
    int r = cid >> 3;
    int g = (cid & 7) ^ (r & 7);
    ap[j] = Ag + (bm + r) * lda + koff + g * 8;
    bp[j] = Bt + (bnn + r) * ldb + koff + g * 8;
    ao[j] = cid * 8;
    bo[j] = 8192 + cid * 8;
  }

  // prologue: stage buffer 0 (8 vmem ops/thread)
#pragma unroll
  for (int j = 0; j < 4; ++j) gload_lds16(ap[j], smem + ao[j]);
#pragma unroll
  for (int j = 0; j < 4; ++j) gload_lds16(bp[j], smem + bo[j]);

  const int nsteps = K >> 6;
  for (int s = 0; s < nsteps; ++s) {
    const int cur = s & 1;
    u16* buf = smem + cur * 16384;
    if (s + 1 < nsteps) {
      u16* nb = smem + (cur ^ 1) * 16384;
      const int k1 = (s + 1) << 6;
#pragma unroll
      for (int j = 0; j < 4; ++j) gload_lds16(ap[j] + k1, nb + ao[j]);
#pragma unroll
      for (int j = 0; j < 4; ++j) gload_lds16(bp[j] + k1, nb + bo[j]);
      asm volatile("s_waitcnt vmcnt(8)" ::: "memory");  // cur's 8 done; prefetch in flight
    } else {
      asm volatile("s_waitcnt vmcnt(0)" ::: "memory");
    }
    __builtin_amdgcn_sched_barrier(0);
    __builtin_amdgcn_s_barrier();
    __builtin_amdgcn_sched_barrier(0);
    u16* As = buf;
    u16* Bs = buf + 8192;
#pragma unroll
    for (int sub = 0; sub < 2; ++sub) {
      const int gg = q4 + sub * 4;
      bf16x8 av[4], bv[4];
#pragma unroll
      for (int i = 0; i < 4; ++i) {
        int r = wm + i * 16 + r16;
        av[i] = *reinterpret_cast<const bf16x8*>(As + (r * 8 + (gg ^ (r & 7))) * 8);
      }
#pragma unroll
      for (int j2 = 0; j2 < 4; ++j2) {
        int r = wn + j2 * 16 + r16;
        bv[j2] = *reinterpret_cast<const bf16x8*>(Bs + (r * 8 + (gg ^ (r & 7))) * 8);
      }
#pragma unroll
      for (int i = 0; i < 4; ++i)
#pragma unroll
        for (int j2 = 0; j2 < 4; ++j2)
          acc[i][j2] = __builtin_amdgcn_mfma_f32_16x16x32_bf16(av[i], bv[j2], acc[i][j2], 0, 0, 0);
    }
    __builtin_amdgcn_sched_barrier(0);
    __builtin_amdgcn_s_barrier();  // all reads of buf retired before restage
    __builtin_amdgcn_sched_barrier(0);
  }

  if (EPI == 3) {
    // f32 out: stage per-wave half-tiles -> f32x4 stores (smem free after last barrier)
    float* Cz = (float*)C + (long)blockIdx.z * zstride;
    float* epf = (float*)smem + w * 2048;
#pragma unroll
    for (int half = 0; half < 2; ++half) {
#pragma unroll
      for (int i = 0; i < 2; ++i)
#pragma unroll
        for (int j = 0; j < 4; ++j)
#pragma unroll
          for (int r = 0; r < 4; ++r)
            epf[(i * 16 + q4 * 4 + r) * 64 + j * 16 + r16] = acc[half * 2 + i][j][r];
      __syncthreads();
#pragma unroll
      for (int v2 = 0; v2 < 8; ++v2) {
        int idx = v2 * 64 + lane;
        int row = idx >> 4, c4 = (idx & 15) * 4;
        f32x4 vec = *(const f32x4*)(epf + row * 64 + c4);
        long grow = bm + wm + half * 32 + row;
        int gcol = (int)bnn + wn + c4;
        if (gcol < Nreal) *(f32x4*)(Cz + grow * (long)ldc + gcol) = vec;
      }
      __syncthreads();
    }
  } else if (EPI == 4) {
    // fused gate-head; per-row dot with W_g2 (2 cols), no h1 materialization
    float bcol[4], w0[4], w1[4];
#pragma unroll
    for (int j = 0; j < 4; ++j) {
      int gc = (int)bnn + wn + j * 16 + r16;
      bcol[j] = bias[gc];
      w0[j] = W_g2[gc * 2];
      w1[j] = W_g2[gc * 2 + 1];
    }
#pragma unroll
    for (int i = 0; i < 4; ++i)
#pragma unroll
      for (int r = 0; r < 4; ++r) {
        float a0 = 0.f, a1 = 0.f;
#pragma unroll
        for (int j = 0; j < 4; ++j) {
          float h = gelu_f(acc[i][j][r] + bcol[j]);
          a0 += h * w0[j];
          a1 += h * w1[j];
        }
#pragma unroll
        for (int off = 1; off < 16; off <<= 1) {
          a0 += __shfl_xor(a0, off);
          a1 += __shfl_xor(a1, off);
        }
        if (r16 == 0) {
          long row = bm + wm + i * 16 + q4 * 4 + r;
          atomicAdd(&gatel[row * 2], a0);
          atomicAdd(&gatel[row * 2 + 1], a1);
        }
      }
  } else {
    // bf16 out (+bias, optional gelu): two 32-row half-tiles, stride-72 staging
    u16* ep = smem + w * 2304;
    float bcol[4];
#pragma unroll
    for (int j = 0; j < 4; ++j) bcol[j] = bias[bnn + wn + j * 16 + r16];
#pragma unroll
    for (int half = 0; half < 2; ++half) {
#pragma unroll
      for (int i = 0; i < 2; ++i)
#pragma unroll
        for (int j = 0; j < 4; ++j)
#pragma unroll
          for (int r = 0; r < 4; ++r) {
            float v = acc[half * 2 + i][j][r] + bcol[j];
            if (EPI == 1) v = gelu_f(v);
            ep[(i * 16 + q4 * 4 + r) * 72 + j * 16 + r16] = f2bf(v);
          }
      __syncthreads();
#pragma unroll
      for (int v2 = 0; v2 < 4; ++v2) {
        int row = v2 * 8 + (lane >> 3);
        int c8 = (lane & 7) * 8;
        u16x8 vec = *(const u16x8*)(ep + row * 72 + c8);
        long grow = bm + wm + half * 32 + row;
        int gcol = (int)bnn + wn + c8;
        if (gcol < Nreal) *(u16x8*)((u16*)C + grow * (long)ldc + gcol) = vec;
      }
      __syncthreads();
    }
  }
}

// ---------------- top-8 per row + fused gather of retrieved rows ----------------
DEV bool better(float v1, int i1, float v2, int i2) {
  return v1 > v2 || (v1 == v2 && i1 < i2);
}
__global__ __launch_bounds__(256) void topk_kernel(const float* __restrict__ sim,
                                                   int* __restrict__ idxout,
                                                   const float* __restrict__ mb,
                                                   u16* __restrict__ retrB) {
  const int bn = blockIdx.x;
  const int tid = threadIdx.x;
  const float* row = sim + (long)bn * 8192;
  float bv[8]; int bi[8];
#pragma unroll
  for (int r = 0; r < 8; ++r) { bv[r] = -3.0e38f; bi[r] = 0x7fffffff; }
  for (int n = tid; n < 8192; n += 256) {
    float v = row[n];
    if (better(v, n, bv[7], bi[7])) {
      bv[7] = v; bi[7] = n;
      for (int r = 7; r > 0; --r) {
        if (!better(bv[r], bi[r], bv[r - 1], bi[r - 1])) break;
        float tv = bv[r]; bv[r] = bv[r - 1]; bv[r - 1] = tv;
        int ti = bi[r]; bi[r] = bi[r - 1]; bi[r - 1] = ti;
      }
    }
  }
  __shared__ float lv[256 * 8];
  __shared__ int li[256 * 8];
#pragma unroll
  for (int r = 0; r < 8; ++r) { lv[tid * 8 + r] = bv[r]; li[tid * 8 + r] = bi[r]; }
  __syncthreads();
  for (int step = 128; step >= 1; step >>= 1) {
    if (tid < step) {
      float av[8], xv[8]; int ai[8], xi[8];
#pragma unroll
      for (int r = 0; r < 8; ++r) {
        av[r] = lv[tid * 8 + r]; ai[r] = li[tid * 8 + r];
        xv[r] = lv[(tid + step) * 8 + r]; xi[r] = li[(tid + step) * 8 + r];
      }
      int ia = 0, ib = 0;
      float mv[8]; int mi[8];
#pragma unroll
      for (int r = 0; r < 8; ++r) {
        if (better(av[ia], ai[ia], xv[ib], xi[ib])) { mv[r] = av[ia]; mi[r] = ai[ia]; ++ia; }
        else { mv[r] = xv[ib]; mi[r] = xi[ib]; ++ib; }
      }
#pragma unroll
      for (int r = 0; r < 8; ++r) { lv[tid * 8 + r] = mv[r]; li[tid * 8 + r] = mi[r]; }
    }
    __syncthreads();
  }
  if (tid < 8) idxout[bn * 8 + tid] = li[tid];
  // fused gather: 8 rows x 512 cols f32 -> bf16 (li[0..7] valid for all threads)
  for (int e = tid; e < 512; e += 256) {
    int rr = e >> 6, c8 = (e & 63) * 8;
    long r = li[rr];
    if (r < 0) r = 0;
    if (r > 8191) r = 8191;
    const float* src = mb + r * 512 + c8;
    u16x8 o;
#pragma unroll
    for (int z = 0; z < 8; ++z) o[z] = f2bf(src[z]);
    *(u16x8*)(retrB + ((long)bn * 8 + rr) * 512 + c8) = o;
  }
}

// ---------------- mean over K of gelu-hidden -> bf16 (vectorized x8) ------------
__global__ __launch_bounds__(256) void gmean_kernel(const u16* __restrict__ hid,
                                                    u16* __restrict__ gmeanB) {
  int t = blockIdx.x * 256 + threadIdx.x;  // < 131072
  int bn = t >> 7, j8 = (t & 127) * 8;
  float s[8] = {};
#pragma unroll
  for (int k = 0; k < 8; ++k) {
    u16x8 v = *(const u16x8*)(hid + (long)(bn * 8 + k) * 1024 + j8);
#pragma unroll
    for (int z = 0; z < 8; ++z) s[z] += bf2f(v[z]);
  }
  u16x8 o;
#pragma unroll
  for (int z = 0; z < 8; ++z) o[z] = f2bf(s[z] * 0.125f);
  *(u16x8*)(gmeanB + (long)bn * 1024 + j8) = o;
}

// ---------------- MFMA attention; O -> contiguous obuf ---------------------------
__global__ __launch_bounds__(256) void attn_kernel(const u16* __restrict__ qkvb,
                                                   u16* __restrict__ obuf) {
  __shared__ __align__(16) u16 smem[26752];
  u16* Qs = smem;
  u16* Ks = smem + 8704;
  float* ss = (float*)(smem + 8704);   // overlay Ks
  u16* ps = smem;                      // overlay Qs
  u16* Os = smem;                      // overlay Qs/ps after PV operand loads
  u16* Vb = smem + 17408;
  float* red = (float*)(smem + 25728);
  const int bn = blockIdx.x, h = blockIdx.y;
  const int tid = threadIdx.x;
  const int lane = tid & 63, w = tid >> 6;
  const int r16 = lane & 15, q4 = lane >> 4;
  const long base = (long)bn * 64 * 1536 + h * 128;

  for (int c = tid; c < 1024; c += 256) {
    int r = c >> 4, c8 = (c & 15) * 8;
    u16x8 vq = *(const u16x8*)(qkvb + base + (long)r * 1536 + c8);
    u16x8 vk = *(const u16x8*)(qkvb + base + (long)r * 1536 + 512 + c8);
    u16x8 vv = *(const u16x8*)(qkvb + base + (long)r * 1536 + 1024 + c8);
    *(u16x8*)(Qs + r * 136 + c8) = vq;
    *(u16x8*)(Ks + r * 136 + c8) = vk;
    int kt = r >> 5, q4t = (r >> 3) & 3, e = r & 7;
    int nt = c8 >> 4, rb = c8 & 15;
    int vbase = (nt * 2 + kt) * 520 + (q4t * 16 + rb) * 8 + e;
#pragma unroll
    for (int z = 0; z < 8; ++z) Vb[vbase + z * 8] = vv[z];
  }
  __syncthreads();

  const int m0 = w * 16;
  f32x4 accS[4] = {};
#pragma unroll
  for (int k0 = 0; k0 < 128; k0 += 32) {
    bf16x8 av = *(const bf16x8*)(Qs + (m0 + r16) * 136 + k0 + q4 * 8);
#pragma unroll
    for (int j = 0; j < 4; ++j) {
      bf16x8 bvf = *(const bf16x8*)(Ks + (j * 16 + r16) * 136 + k0 + q4 * 8);
      accS[j] = __builtin_amdgcn_mfma_f32_16x16x32_bf16(av, bvf, accS[j], 0, 0, 0);
    }
  }
  __syncthreads();
  const float scale = 0.08838834764831845f;  // 1/sqrt(128)
#pragma unroll
  for (int j = 0; j < 4; ++j)
#pragma unroll
    for (int r = 0; r < 4; ++r)
      ss[(m0 + q4 * 4 + r) * 66 + j * 16 + r16] = accS[j][r] * scale;
  __syncthreads();

  {
    int r = tid >> 2, p = tid & 3;
    float* row = ss + r * 66 + p * 16;
    float mx = -3.0e38f;
#pragma unroll
    for (int c2 = 0; c2 < 16; ++c2) mx = fmaxf(mx, row[c2]);
    red[r * 4 + p] = mx;
    __syncthreads();
    float m4 = fmaxf(fmaxf(red[r * 4], red[r * 4 + 1]),
                     fmaxf(red[r * 4 + 2], red[r * 4 + 3]));
    float s = 0.f;
#pragma unroll
    for (int c2 = 0; c2 < 16; ++c2) {
      float e = expf(row[c2] - m4);
      row[c2] = e;
      s += e;
    }
    red[256 + r * 4 + p] = s;
    __syncthreads();
    float inv = 1.f / (red[256 + r * 4] + red[256 + r * 4 + 1] +
                       red[256 + r * 4 + 2] + red[256 + r * 4 + 3]);
    u16x8 o0, o1;
#pragma unroll
    for (int z = 0; z < 8; ++z) {
      o0[z] = f2bf(row[z] * inv);
      o1[z] = f2bf(row[8 + z] * inv);
    }
    *(u16x8*)(ps + r * 72 + p * 16) = o0;
    *(u16x8*)(ps + r * 72 + p * 16 + 8) = o1;
  }
  __syncthreads();

  bf16x8 av0 = *(const bf16x8*)(ps + (m0 + r16) * 72 + q4 * 8);
  bf16x8 av1 = *(const bf16x8*)(ps + (m0 + r16) * 72 + 32 + q4 * 8);
  __syncthreads();  // everyone done reading ps before Os overwrites it
#pragma unroll
  for (int nt = 0; nt < 8; ++nt) {
    f32x4 accO = {};
    bf16x8 bv0 = *(const bf16x8*)(Vb + (nt * 2 + 0) * 520 + lane * 8);
    bf16x8 bv1 = *(const bf16x8*)(Vb + (nt * 2 + 1) * 520 + lane * 8);
    accO = __builtin_amdgcn_mfma_f32_16x16x32_bf16(av0, bv0, accO, 0, 0, 0);
    accO = __builtin_amdgcn_mfma_f32_16x16x32_bf16(av1, bv1, accO, 0, 0, 0);
#pragma unroll
    for (int r = 0; r < 4; ++r) {
      int i = m0 + q4 * 4 + r;
      int col = nt * 16 + r16;
      Os[i * 128 + (col ^ (q4 << 4))] = f2bf(accO[r]);
    }
  }
  __syncthreads();
  // coalesced store: O rows -> obuf [65536 x 512], head h at cols h*128..h*128+127
#pragma unroll
  for (int z = 0; z < 4; ++z) {
    int idx = z * 256 + tid;
    int row = idx >> 4, c8 = (idx & 15) * 8;
    int c8s = c8 ^ (((row >> 2) & 3) << 4);
    u16x8 vec = *(const u16x8*)(Os + row * 128 + c8s);
    *(u16x8*)(obuf + ((long)bn * 64 + row) * 512 + h * 128 + c8) = vec;
  }
}

// ------- local = emb + (sum of 4 hmean K-slices + b_m2) -> locglob cols 0-511 ----
__global__ __launch_bounds__(256) void local_kernel(const u16* __restrict__ embh,
                                                    const float* __restrict__ hs,
                                                    const float* __restrict__ b_m2,
                                                    u16* __restrict__ locglob) {
  long t = (long)blockIdx.x * 256 + threadIdx.x;  // < 4194304
  long e8 = t * 8;
  long m = e8 >> 9;
  int d = (int)(e8 & 511);
  int bn = (int)(m >> 6);
  u16x8 a = *(const u16x8*)(embh + e8);
  float h[8];
#pragma unroll
  for (int z = 0; z < 8; ++z) h[z] = b_m2[d + z];
#pragma unroll
  for (int zz = 0; zz < 4; ++zz) {
    const float* sp = hs + (long)zz * 524288 + (long)bn * 512 + d;
#pragma unroll
    for (int z = 0; z < 8; ++z) h[z] += sp[z];
  }
  u16x8 o;
#pragma unroll
  for (int z = 0; z < 8; ++z) o[z] = f2bf(bf2f(a[z]) + h[z]);
  *(u16x8*)(locglob + m * 1024 + d) = o;
}

// ---------------- mem = softmax-gate combine -> embh (vector x8) ----------------
__global__ __launch_bounds__(256) void memc_kernel(u16* __restrict__ embh,
                                                   const u16* __restrict__ locglob,
                                                   const float* __restrict__ gatel,
                                                   const float* __restrict__ b_g2) {
  long t = (long)blockIdx.x * 256 + threadIdx.x;  // < 4194304
  long e8 = t * 8;
  long m = e8 >> 9;
  int d = (int)(e8 & 511);
  float l0 = gatel[m * 2] + b_g2[0];
  float l1 = gatel[m * 2 + 1] + b_g2[1];
  float mx = fmaxf(l0, l1);
  float e0 = expf(l0 - mx), e1 = expf(l1 - mx);
  float inv = 1.f / (e0 + e1);
  float g0 = e0 * inv, g1 = e1 * inv;
  u16x8 loc = *(const u16x8*)(locglob + m * 1024 + d);
  u16x8 gl = *(const u16x8*)(locglob + m * 1024 + 512 + d);
  u16x8 o;
#pragma unroll
  for (int z = 0; z < 8; ++z) o[z] = f2bf(g0 * bf2f(loc[z]) + g1 * bf2f(gl[z]));
  *(u16x8*)(embh + e8) = o;
}

// ---------------- fusion head + denorm + transpose store (f32) ----------------
// mh32: 32 split-K slices of [1024,192]; summed here (replaces global atomics)
__global__ __launch_bounds__(256) void fusion_kernel(const float* __restrict__ mh32,
                                                     const float* __restrict__ b_h,
                                                     const float* __restrict__ W_f1,
                                                     const float* __restrict__ b_f1,
                                                     const float* __restrict__ W_f2,
                                                     const float* __restrict__ b_f2,
                                                     const float* __restrict__ meanv,
                                                     const float* __restrict__ stdv,
                                                     float* __restrict__ out) {
  int bn = blockIdx.x;
  int tid = threadIdx.x;
  __shared__ float mrow[192];
  __shared__ float h1[384];
  if (tid < 192) {
    float a = b_h[tid];
#pragma unroll
    for (int z = 0; z < 32; ++z) a += mh32[(long)z * 196608 + (long)bn * 192 + tid];
    mrow[tid] = a;
  }
  __syncthreads();
  for (int j = tid; j < 384; j += 256) {
    float a = b_f1[j];
    for (int i = 0; i < 192; ++i) a += mrow[i] * W_f1[i * 384 + j];
    h1[j] = gelu_f(a);
  }
  __syncthreads();
  if (tid < 192) {
    float a = b_f2[tid];
    for (int j = 0; j < 384; ++j) a += h1[j] * W_f2[j * 192 + tid];
    float o = gelu_f(a) + mrow[tid];
    int b = bn >> 6, v = bn & 63;
    out[((long)b * 192 + tid) * 64 + v] = o * stdv[bn] + meanv[bn];
  }
}

extern "C" void kernel_launch(void* const* d_in, const int* in_sizes, int n_in,
                              void* d_out, int out_size, void* d_ws, size_t ws_size,
                              hipStream_t stream) {
  (void)in_sizes; (void)n_in; (void)out_size; (void)d_ws; (void)ws_size;
  const float* x_enc = (const float*)d_in[0];
  const float* W_val = (const float*)d_in[1];
  const float* mem_bank = (const float*)d_in[2];
  const float* W_m1 = (const float*)d_in[3];
  const float* b_m1 = (const float*)d_in[4];
  const float* W_m2 = (const float*)d_in[5];
  const float* b_m2 = (const float*)d_in[6];
  const float* W_q = (const float*)d_in[7];
  const float* b_q = (const float*)d_in[8];
  const float* W_k = (const float*)d_in[9];
  const float* b_k = (const float*)d_in[10];
  const float* W_v = (const float*)d_in[11];
  const float* b_v = (const float*)d_in[12];
  const float* W_o = (const float*)d_in[13];
  const float* b_o = (const float*)d_in[14];
  const float* W_g1 = (const float*)d_in[15];
  const float* b_g1 = (const float*)d_in[16];
  const float* W_g2 = (const float*)d_in[17];
  const float* b_g2 = (const float*)d_in[18];
  const float* W_h = (const float*)d_in[19];
  const float* b_h = (const float*)d_in[20];
  const float* W_f1 = (const float*)d_in[21];
  const float* b_f1 = (const float*)d_in[22];
  const float* W_f2 = (const float*)d_in[23];
  const float* b_f2 = (const float*)d_in[24];

  void* sp = nullptr;
  hipGetSymbolAddress(&sp, HIP_SYMBOL(g_s));
  Scratch* S = (Scratch*)sp;
  // sim-phase aliases inside qkvb (all dead before fused QKV writes it)
  float* simB = (float*)S->qkvb;                            // 32 MB
  u16* qsC = S->qkvb + (size_t)16 * 1024 * 1024;            // 3 MB
  u16* retrB = S->qkvb + (size_t)18 * 1024 * 1024;          // 8 MB
  u16* hiddenB = S->qkvb + (size_t)24 * 1024 * 1024;        // 16 MB
  // mh split-K slices alias qkvb (dead after memc); hmean slices live in obuf
  float* mh32 = (float*)S->qkvb;                            // 25 MB
  float* hs = (float*)S->obuf;                              // 8 MB (obuf dead until attn)

  // merged setup: pos/stats/zeros/bias/8 transposes/memdup in ONE launch
  prep_kernel<<<12374, 256, 0, stream>>>(x_enc, b_q, b_k, b_v, W_q, W_k, W_v, W_o,
                                         W_m1, W_m2, W_g1, W_h, mem_bank);
  // embedding (writes embh + fused [qh|ql|qh] sim-query rows)
  emb_kernel<<<1024, 256, 0, stream>>>(x_enc, W_val, S->POSb, S->meanv, S->stdv,
                                       S->embh, qsC);
  // retrieval sim: Mtiles=8, nT=64 -> grid 512
  gemm_db<3><<<512, 256, 0, stream>>>(qsC, S->memdupB, nullptr, simB, nullptr, nullptr,
                                      1536, 1536, 1536, 8192, 8192, 64, 0L);
  // topk + fused gather
  topk_kernel<<<1024, 256, 0, stream>>>(simB, S->idxB, mem_bank, retrB);
  // Wm1: Mtiles=64, nT=8 -> grid 512
  gemm_db<1><<<512, 256, 0, stream>>>(retrB, S->Wm1T, b_m1, hiddenB, nullptr, nullptr,
                                      512, 512, 512, 1024, 1024, 8, 0L);
  gmean_kernel<<<512, 256, 0, stream>>>(hiddenB, S->gmeanB);
  // hmean: split-K z=4 (K=256/slice) -> f32 slices in obuf; bias added in local
  gemm_db<3><<<dim3(32, 1, 4), 256, 0, stream>>>(S->gmeanB, S->Wm2T, nullptr, hs,
                                                 nullptr, nullptr,
                                                 1024, 1024, 256, 512, 512, 4, 524288L);
  // fused QKV: Mtiles=512, nT=12 -> grid 6144
  gemm_db<0><<<6144, 256, 0, stream>>>(S->embh, S->WqkvT, S->bqkv, S->qkvb, nullptr, nullptr,
                                       512, 512, 512, 1536, 1536, 12, 0L);
  // local = emb + (sum hmean slices + b_m2) -> locglob[:, 0:512]
  local_kernel<<<16384, 256, 0, stream>>>(S->embh, hs, b_m2, S->locglob);
  // attention: O -> contiguous obuf (overwrites hmean slices; local already consumed)
  attn_kernel<<<dim3(1024, 4), 256, 0, stream>>>(S->qkvb, S->obuf);
  // glob = O @ W_o + b_o -> locglob[:, 512:1024] (contiguous A)
  gemm_db<0><<<2048, 256, 0, stream>>>(S->obuf, S->WoT, b_o, S->locglob + 512, nullptr, nullptr,
                                       512, 512, 512, 512, 1024, 4, 0L);
  // gate logits: single-source K=1024 GEMM + fused gate epilogue
  gemm_db<4><<<2048, 256, 0, stream>>>(S->locglob, S->Wg1T, b_g1, nullptr,
                                       W_g2, S->gatel, 1024, 1024, 1024, 512, 0, 4, 0L);
  // mem = softmax(gate)-combine of locglob halves -> embh
  memc_kernel<<<16384, 256, 0, stream>>>(S->embh, S->locglob, S->gatel, b_g2);
  // mh = mem_flat [1024,32768] @ WhT^T, split-K z=32 (K=1024/slice) -> f32 slices
  gemm_db<3><<<dim3(16, 1, 32), 256, 0, stream>>>(S->embh, S->WhT, nullptr, mh32,
                                                  nullptr, nullptr,
                                                  32768, 32768, 1024, 192, 192, 2,
                                                  196608L);
  fusion_kernel<<<1024, 256, 0, stream>>>(mh32, b_h, W_f1, b_f1, W_f2, b_f2,
                                          S->meanv, S->stdv, (float*)d_out);
}

// Round 8
// 980.813 us; speedup vs baseline: 1.0341x; 1.0341x over previous
//
#include <hip/hip_runtime.h>
#include <stdint.h>

#define DEV __device__ __forceinline__

typedef uint16_t u16;
typedef __bf16 bf16x8 __attribute__((ext_vector_type(8)));
typedef float f32x4 __attribute__((ext_vector_type(4)));
typedef u16 u16x8 __attribute__((ext_vector_type(8)));

DEV float bf2f(u16 v) { return __uint_as_float(((uint32_t)v) << 16); }
DEV u16 f2bf(float f) {
  uint32_t u = __float_as_uint(f);
  u += 0x7fffu + ((u >> 16) & 1u);
  return (u16)(u >> 16);
}
DEV float gelu_f(float x) { return 0.5f * x * (1.0f + erff(x * 0.7071067811865475f)); }

DEV void gload_lds16(const u16* g, u16* l) {
  __builtin_amdgcn_global_load_lds(
      (const __attribute__((address_space(1))) void*)g,
      (__attribute__((address_space(3))) void*)l, 16, 0, 0);
}

// ---- all scratch in a static device global (R4: never trust ws_size) ----
struct __align__(16) Scratch {
  float POSb[64 * 512];
  float meanv[1024];
  float stdv[1024];
  float mh[1024 * 192];
  int idxB[8192];
  float qflat[1024 * 512];
  float gatel[65536 * 2];
  float bqkv[1536];
  u16 hmeanB[1024 * 512];
  u16 gmeanB[1024 * 1024];
  u16 WqkvT[1536 * 512];       // rows 0-511 Wq^T, 512-1023 Wk^T, 1024-1535 Wv^T
  u16 WoT[512 * 512];
  u16 Wm1T[1024 * 512];
  u16 Wm2T[512 * 1024];
  u16 Wg1T[512 * 1024];
  u16 WhT[256 * 32768];        // rows 192..255 zero-filled
  u16 memdupB[8192 * 1536];    // [mh|mh|ml] 24 MB
  u16 embh[65536 * 512];       // 64 MB: emb -> mem (memc result, feeds mh)
  u16 locglob[65536 * 1024];   // 128 MB: [local | glob] contiguous rows
  u16 obuf[65536 * 512];       // 64 MB: attention O, contiguous
  u16 qkvb[65536 * 1536];      // 192 MB: Q|K|V (sim aliases + mh slices live here)
};
__device__ Scratch g_s;

// ---------------- fills / small setup ----------------
__global__ __launch_bounds__(256) void zerof_kernel(float* __restrict__ p, int n) {
  int t = blockIdx.x * 256 + threadIdx.x;
  if (t < n) p[t] = 0.f;
}
__global__ __launch_bounds__(256) void zerou8_kernel(u16* __restrict__ p, int n8) {
  int t = blockIdx.x * 256 + threadIdx.x;
  if (t < n8) *(u16x8*)(p + (long)t * 8) = (u16x8)0;
}
__global__ __launch_bounds__(256) void biasqkv_kernel(const float* __restrict__ bq,
                                                      const float* __restrict__ bk,
                                                      const float* __restrict__ bv,
                                                      float* __restrict__ o) {
  int t = blockIdx.x * 256 + threadIdx.x;  // < 1536
  o[t] = t < 512 ? bq[t] : (t < 1024 ? bk[t - 512] : bv[t - 1024]);
}

// ---------------- POS embedding ----------------
__global__ __launch_bounds__(256) void pos_kernel(float* __restrict__ POS) {
  int n = blockIdx.x;
  int i = threadIdx.x;
  float div = expf((float)(2 * i) * (-9.210340371976184f / 512.0f));
  float arg = (float)n * div;
  POS[n * 512 + 2 * i] = sinf(arg);
  POS[n * 512 + 2 * i + 1] = cosf(arg);
}

// ---------------- instance-norm stats ----------------
__global__ __launch_bounds__(256) void stats_kernel(const float* __restrict__ x_enc,
                                                    float* __restrict__ meanv,
                                                    float* __restrict__ stdv) {
  int b = blockIdx.x;
  int v = threadIdx.x & 63;
  int g = threadIdx.x >> 6;
  float s = 0.f, s2 = 0.f;
  for (int l = g; l < 512; l += 4) {
    float x = x_enc[((long)b * 512 + l) * 64 + v];
    s += x; s2 += x * x;
  }
  __shared__ float sh[2][4][64];
  sh[0][g][v] = s; sh[1][g][v] = s2;
  __syncthreads();
  if (g == 0) {
    s = sh[0][0][v] + sh[0][1][v] + sh[0][2][v] + sh[0][3][v];
    s2 = sh[1][0][v] + sh[1][1][v] + sh[1][2][v] + sh[1][3][v];
    float mu = s * (1.f / 512.f);
    float var = s2 * (1.f / 512.f) - mu * mu;
    meanv[b * 64 + v] = mu;
    stdv[b * 64 + v] = sqrtf(var + 1e-5f) * 2.5f;  // sqrt(var+eps)/0.4
  }
}

// ---------------- transpose f32 [R,C] -> bf16 [C,R] ----------------
__global__ __launch_bounds__(256) void transpose_kernel(const float* __restrict__ in,
                                                        u16* __restrict__ out, int R, int C) {
  __shared__ u16 t[32][33];
  int bx = blockIdx.x * 32;
  int by = blockIdx.y * 32;
  int tx = threadIdx.x & 31, ty = threadIdx.x >> 5;
  for (int i = ty; i < 32; i += 8) t[i][tx] = f2bf(in[(long)(by + i) * C + bx + tx]);
  __syncthreads();
  for (int i = ty; i < 32; i += 8) out[(long)(bx + i) * R + by + tx] = t[tx][i];
}

// ---------------- patch embed + fused qflat->[qh|ql|qh] row ----------------
__global__ __launch_bounds__(256) void emb_kernel(const float* __restrict__ x_enc,
                                                  const float* __restrict__ W_val,
                                                  const float* __restrict__ POS,
                                                  const float* __restrict__ meanv,
                                                  const float* __restrict__ stdv,
                                                  u16* __restrict__ embh,
                                                  u16* __restrict__ qsC) {
  int bn = blockIdx.x;
  int b = bn >> 6, v = bn & 63;
  int tid = threadIdx.x;
  __shared__ __align__(16) float wv[16 * 512];
  __shared__ __align__(16) float pt[64 * 16];
  for (int i = tid; i < 8192; i += 256) wv[i] = W_val[i];
  float mu = meanv[bn];
  float inv = 1.f / stdv[bn];
  for (int i = tid; i < 1024; i += 256) {
    int n = i >> 4, p = i & 15;
    int l = n * 8 + p; if (l > 511) l = 511;  // replication pad
    pt[i] = (x_enc[((long)b * 512 + l) * 64 + v] - mu) * inv;
  }
  __syncthreads();
  float qs0 = 0.f, qs1 = 0.f;
  int d0 = tid, d1 = tid + 256;
  for (int n = 0; n < 64; ++n) {
    float a0 = POS[n * 512 + d0], a1 = POS[n * 512 + d1];
#pragma unroll
    for (int p = 0; p < 16; ++p) {
      float pv = pt[n * 16 + p];
      a0 += pv * wv[p * 512 + d0];
      a1 += pv * wv[p * 512 + d1];
    }
    long base = ((long)bn * 64 + n) * 512;
    embh[base + d0] = f2bf(a0);
    embh[base + d1] = f2bf(a1);
    qs0 += a0; qs1 += a1;
  }
  float q0 = qs0 * (1.f / 64.f), q1 = qs1 * (1.f / 64.f);
  u16 h0 = f2bf(q0), l0 = f2bf(q0 - bf2f(h0));
  u16 h1 = f2bf(q1), l1 = f2bf(q1 - bf2f(h1));
  long qb = (long)bn * 1536;
  qsC[qb + d0] = h0; qsC[qb + 512 + d0] = l0; qsC[qb + 1024 + d0] = h0;
  qsC[qb + d1] = h1; qsC[qb + 512 + d1] = l1; qsC[qb + 1024 + d1] = h1;
}

// ---------------- mem_bank f32 -> [mh|mh|ml] bf16 row of 1536 (vectorized x8) ---
__global__ __launch_bounds__(256) void memdup_kernel(const float* __restrict__ mb,
                                                     u16* __restrict__ md) {
  int t = blockIdx.x * 256 + threadIdx.x;  // < 524288
  int n = t >> 6, k8 = (t & 63) * 8;
  const float* src = mb + (long)n * 512 + k8;
  u16x8 hi, lo;
#pragma unroll
  for (int z = 0; z < 8; ++z) {
    float m = src[z];
    u16 h = f2bf(m);
    hi[z] = h;
    lo[z] = f2bf(m - bf2f(h));
  }
  long base = (long)n * 1536 + k8;
  *(u16x8*)(md + base) = hi;
  *(u16x8*)(md + base + 512) = hi;
  *(u16x8*)(md + base + 1024) = lo;
}

// ---------------- double-buffered NT GEMM (T3 minimum 2-phase, counted vmcnt) -----
// 128x128 tile, 256 threads. EPI: 0 bias+bf16 | 1 bias+gelu+bf16 | 3 f32 z-sliced |
// 4 fused gate-logit epilogue.
template <int EPI>
__global__ __launch_bounds__(256) void gemm_db(const u16* __restrict__ Ag,
                                               const u16* __restrict__ Bt,
                                               const float* __restrict__ bias,
                                               void* __restrict__ C,
                                               const float* __restrict__ W_g2,
                                               float* __restrict__ gatel,
                                               int lda, int ldb, int K, int Nreal, int ldc,
                                               int nT, long zstride) {
  __shared__ __align__(16) u16 smem[4 * 128 * 64];  // 64 KB: 2 x (As 16K + Bs 16K)
  const int tid = threadIdx.x;
  const int id = blockIdx.x;
  const int xcd = id & 7;
  const int kk = id >> 3;
  const long bm = (long)((kk / nT) * 8 + xcd) * 128;
  const long bnn = (long)(kk % nT) * 128;
  const long koff = (long)blockIdx.z * (long)K;
  const int lane = tid & 63;
  const int w = tid >> 6;
  const int wm = (w & 1) * 64;
  const int wn = (w >> 1) * 64;
  const int r16 = lane & 15;
  const int q4 = lane >> 4;

  f32x4 acc[4][4] = {};

  const u16* ap[4];
  const u16* bp[4];
  int ao[4], bo[4];
#pragma unroll
  for (int j = 0; j < 4; ++j) {
    int cid = (j * 4 + w) * 64 + lane;
    int r = cid >> 3;
    int g = (cid & 7) ^ (r & 7);
    ap[j] = Ag + (bm + r) * lda + koff + g * 8;
    bp[j] = Bt + (bnn + r) * ldb + koff + g * 8;
    ao[j] = cid * 8;
    bo[j] = 8192 + cid * 8;
  }

  // prologue: stage buffer 0 (8 vmem ops/thread)
#pragma unroll
  for (int j = 0; j < 4; ++j) gload_lds16(ap[j], smem + ao[j]);
#pragma unroll
  for (int j = 0; j < 4; ++j) gload_lds16(bp[j], smem + bo[j]);

  const int nsteps = K >> 6;
  for (int s = 0; s < nsteps; ++s) {
    const int cur = s & 1;
    u16* buf = smem + cur * 16384;
    if (s + 1 < nsteps) {
      u16* nb = smem + (cur ^ 1) * 16384;
      const int k1 = (s + 1) << 6;
#pragma unroll
      for (int j = 0; j < 4; ++j) gload_lds16(ap[j] + k1, nb + ao[j]);
#pragma unroll
      for (int j = 0; j < 4; ++j) gload_lds16(bp[j] + k1, nb + bo[j]);
      asm volatile("s_waitcnt vmcnt(8)" ::: "memory");  // cur's 8 done; prefetch in flight
    } else {
      asm volatile("s_waitcnt vmcnt(0)" ::: "memory");
    }
    __builtin_amdgcn_sched_barrier(0);
    __builtin_amdgcn_s_barrier();
    __builtin_amdgcn_sched_barrier(0);
    u16* As = buf;
    u16* Bs = buf + 8192;
#pragma unroll
    for (int sub = 0; sub < 2; ++sub) {
      const int gg = q4 + sub * 4;
      bf16x8 av[4], bv[4];
#pragma unroll
      for (int i = 0; i < 4; ++i) {
        int r = wm + i * 16 + r16;
        av[i] = *reinterpret_cast<const bf16x8*>(As + (r * 8 + (gg ^ (r & 7))) * 8);
      }
#pragma unroll
      for (int j2 = 0; j2 < 4; ++j2) {
        int r = wn + j2 * 16 + r16;
        bv[j2] = *reinterpret_cast<const bf16x8*>(Bs + (r * 8 + (gg ^ (r & 7))) * 8);
      }
#pragma unroll
      for (int i = 0; i < 4; ++i)
#pragma unroll
        for (int j2 = 0; j2 < 4; ++j2)
          acc[i][j2] = __builtin_amdgcn_mfma_f32_16x16x32_bf16(av[i], bv[j2], acc[i][j2], 0, 0, 0);
    }
    __builtin_amdgcn_sched_barrier(0);
    __builtin_amdgcn_s_barrier();  // all reads of buf retired before restage
    __builtin_amdgcn_sched_barrier(0);
  }

  if (EPI == 3) {
    // f32 out: stage per-wave half-tiles -> f32x4 stores (smem free after last barrier)
    float* Cz = (float*)C + (long)blockIdx.z * zstride;
    float* epf = (float*)smem + w * 2048;
#pragma unroll
    for (int half = 0; half < 2; ++half) {
#pragma unroll
      for (int i = 0; i < 2; ++i)
#pragma unroll
        for (int j = 0; j < 4; ++j)
#pragma unroll
          for (int r = 0; r < 4; ++r)
            epf[(i * 16 + q4 * 4 + r) * 64 + j * 16 + r16] = acc[half * 2 + i][j][r];
      __syncthreads();
#pragma unroll
      for (int v2 = 0; v2 < 8; ++v2) {
        int idx = v2 * 64 + lane;
        int row = idx >> 4, c4 = (idx & 15) * 4;
        f32x4 vec = *(const f32x4*)(epf + row * 64 + c4);
        long grow = bm + wm + half * 32 + row;
        int gcol = (int)bnn + wn + c4;
        if (gcol < Nreal) *(f32x4*)(Cz + grow * (long)ldc + gcol) = vec;
      }
      __syncthreads();
    }
  } else if (EPI == 4) {
    // fused gate-head; per-row dot with W_g2 (2 cols), no h1 materialization
    float bcol[4], w0[4], w1[4];
#pragma unroll
    for (int j = 0; j < 4; ++j) {
      int gc = (int)bnn + wn + j * 16 + r16;
      bcol[j] = bias[gc];
      w0[j] = W_g2[gc * 2];
      w1[j] = W_g2[gc * 2 + 1];
    }
#pragma unroll
    for (int i = 0; i < 4; ++i)
#pragma unroll
      for (int r = 0; r < 4; ++r) {
        float a0 = 0.f, a1 = 0.f;
#pragma unroll
        for (int j = 0; j < 4; ++j) {
          float h = gelu_f(acc[i][j][r] + bcol[j]);
          a0 += h * w0[j];
          a1 += h * w1[j];
        }
#pragma unroll
        for (int off = 1; off < 16; off <<= 1) {
          a0 += __shfl_xor(a0, off);
          a1 += __shfl_xor(a1, off);
        }
        if (r16 == 0) {
          long row = bm + wm + i * 16 + q4 * 4 + r;
          atomicAdd(&gatel[row * 2], a0);
          atomicAdd(&gatel[row * 2 + 1], a1);
        }
      }
  } else {
    // bf16 out (+bias, optional gelu): two 32-row half-tiles, stride-72 staging
    u16* ep = smem + w * 2304;
    float bcol[4];
#pragma unroll
    for (int j = 0; j < 4; ++j) bcol[j] = bias[bnn + wn + j * 16 + r16];
#pragma unroll
    for (int half = 0; half < 2; ++half) {
#pragma unroll
      for (int i = 0; i < 2; ++i)
#pragma unroll
        for (int j = 0; j < 4; ++j)
#pragma unroll
          for (int r = 0; r < 4; ++r) {
            float v = acc[half * 2 + i][j][r] + bcol[j];
            if (EPI == 1) v = gelu_f(v);
            ep[(i * 16 + q4 * 4 + r) * 72 + j * 16 + r16] = f2bf(v);
          }
      __syncthreads();
#pragma unroll
      for (int v2 = 0; v2 < 4; ++v2) {
        int row = v2 * 8 + (lane >> 3);
        int c8 = (lane & 7) * 8;
        u16x8 vec = *(const u16x8*)(ep + row * 72 + c8);
        long grow = bm + wm + half * 32 + row;
        int gcol = (int)bnn + wn + c8;
        if (gcol < Nreal) *(u16x8*)((u16*)C + grow * (long)ldc + gcol) = vec;
      }
      __syncthreads();
    }
  }
}

// ------------- big-tile variant: BM=256 x BN=128, 512 threads (8 waves 4Mx2N) -----
// Same proven 2-phase schedule; per-wave output identical 64x64 acc[4][4].
// 32 MFMA per barrier-pair per wave (2x gemm_db). 96 KB dynamic LDS (2 x 48 KB).
// Staging: 4 A-loads + 2 B-loads per thread per K-tile -> counted vmcnt(6).
// EPI: 0 bias+bf16 | 1 bias+gelu+bf16 | 4 gate-logit epilogue
template <int EPI>
__global__ __launch_bounds__(512) void gemm_db2(const u16* __restrict__ Ag,
                                                const u16* __restrict__ Bt,
                                                const float* __restrict__ bias,
                                                void* __restrict__ C,
                                                const float* __restrict__ W_g2,
                                                float* __restrict__ gatel,
                                                int lda, int ldb, int K, int Nreal, int ldc,
                                                int nT) {
  extern __shared__ __align__(16) u16 smem[];  // 96 KB: 2 x (As 32K + Bs 16K)
  const int tid = threadIdx.x;
  const int id = blockIdx.x;
  const int xcd = id & 7;
  const int kk = id >> 3;
  const long bm = (long)((kk / nT) * 8 + xcd) * 256;
  const long bnn = (long)(kk % nT) * 128;
  const int lane = tid & 63;
  const int w = tid >> 6;          // 0..7
  const int wm = (w >> 1) * 64;    // 0,64,128,192
  const int wn = (w & 1) * 64;     // 0,64
  const int r16 = lane & 15;
  const int q4 = lane >> 4;

  f32x4 acc[4][4] = {};

  const u16* ap[4];
  int ao[4];
  const u16* bp[2];
  int bo[2];
#pragma unroll
  for (int j = 0; j < 4; ++j) {
    int cid = j * 512 + tid;  // 0..2047 (A: 256 rows x 8 chunks)
    int r = cid >> 3;
    int g = (cid & 7) ^ (r & 7);
    ap[j] = Ag + (bm + r) * lda + g * 8;
    ao[j] = cid * 8;
  }
#pragma unroll
  for (int j = 0; j < 2; ++j) {
    int cid = j * 512 + tid;  // 0..1023 (B: 128 rows x 8 chunks)
    int r = cid >> 3;
    int g = (cid & 7) ^ (r & 7);
    bp[j] = Bt + (bnn + r) * ldb + g * 8;
    bo[j] = 16384 + cid * 8;
  }

  // prologue: stage buffer 0 (6 vmem ops/thread)
#pragma unroll
  for (int j = 0; j < 4; ++j) gload_lds16(ap[j], smem + ao[j]);
#pragma unroll
  for (int j = 0; j < 2; ++j) gload_lds16(bp[j], smem + bo[j]);

  const int nsteps = K >> 6;
  for (int s = 0; s < nsteps; ++s) {
    const int cur = s & 1;
    u16* buf = smem + cur * 24576;
    if (s + 1 < nsteps) {
      u16* nb = smem + (cur ^ 1) * 24576;
      const int k1 = (s + 1) << 6;
#pragma unroll
      for (int j = 0; j < 4; ++j) gload_lds16(ap[j] + k1, nb + ao[j]);
#pragma unroll
      for (int j = 0; j < 2; ++j) gload_lds16(bp[j] + k1, nb + bo[j]);
      asm volatile("s_waitcnt vmcnt(6)" ::: "memory");  // cur's 6 done; prefetch in flight
    } else {
      asm volatile("s_waitcnt vmcnt(0)" ::: "memory");
    }
    __builtin_amdgcn_sched_barrier(0);
    __builtin_amdgcn_s_barrier();
    __builtin_amdgcn_sched_barrier(0);
    u16* As = buf;
    u16* Bs = buf + 16384;
#pragma unroll
    for (int sub = 0; sub < 2; ++sub) {
      const int gg = q4 + sub * 4;
      bf16x8 av[4], bv[4];
#pragma unroll
      for (int i = 0; i < 4; ++i) {
        int r = wm + i * 16 + r16;  // 0..255
        av[i] = *reinterpret_cast<const bf16x8*>(As + (r * 8 + (gg ^ (r & 7))) * 8);
      }
#pragma unroll
      for (int j2 = 0; j2 < 4; ++j2) {
        int r = wn + j2 * 16 + r16;  // 0..127
        bv[j2] = *reinterpret_cast<const bf16x8*>(Bs + (r * 8 + (gg ^ (r & 7))) * 8);
      }
#pragma unroll
      for (int i = 0; i < 4; ++i)
#pragma unroll
        for (int j2 = 0; j2 < 4; ++j2)
          acc[i][j2] = __builtin_amdgcn_mfma_f32_16x16x32_bf16(av[i], bv[j2], acc[i][j2], 0, 0, 0);
    }
    __builtin_amdgcn_sched_barrier(0);
    __builtin_amdgcn_s_barrier();  // all reads of buf retired before restage
    __builtin_amdgcn_sched_barrier(0);
  }

  if (EPI == 4) {
    // fused gate-head; per-row dot with W_g2 (2 cols)
    float bcol[4], w0[4], w1[4];
#pragma unroll
    for (int j = 0; j < 4; ++j) {
      int gc = (int)bnn + wn + j * 16 + r16;
      bcol[j] = bias[gc];
      w0[j] = W_g2[gc * 2];
      w1[j] = W_g2[gc * 2 + 1];
    }
#pragma unroll
    for (int i = 0; i < 4; ++i)
#pragma unroll
      for (int r = 0; r < 4; ++r) {
        float a0 = 0.f, a1 = 0.f;
#pragma unroll
        for (int j = 0; j < 4; ++j) {
          float h = gelu_f(acc[i][j][r] + bcol[j]);
          a0 += h * w0[j];
          a1 += h * w1[j];
        }
#pragma unroll
        for (int off = 1; off < 16; off <<= 1) {
          a0 += __shfl_xor(a0, off);
          a1 += __shfl_xor(a1, off);
        }
        if (r16 == 0) {
          long row = bm + wm + i * 16 + q4 * 4 + r;
          atomicAdd(&gatel[row * 2], a0);
          atomicAdd(&gatel[row * 2 + 1], a1);
        }
      }
  } else {
    // bf16 out (+bias, optional gelu): two 32-row half-tiles, stride-72 staging
    u16* ep = smem + w * 2304;  // 8 waves x 4.5 KB = 36 KB < 96 KB
    float bcol[4];
#pragma unroll
    for (int j = 0; j < 4; ++j) bcol[j] = bias[bnn + wn + j * 16 + r16];
#pragma unroll
    for (int half = 0; half < 2; ++half) {
#pragma unroll
      for (int i = 0; i < 2; ++i)
#pragma unroll
        for (int j = 0; j < 4; ++j)
#pragma unroll
          for (int r = 0; r < 4; ++r) {
            float v = acc[half * 2 + i][j][r] + bcol[j];
            if (EPI == 1) v = gelu_f(v);
            ep[(i * 16 + q4 * 4 + r) * 72 + j * 16 + r16] = f2bf(v);
          }
      __syncthreads();
#pragma unroll
      for (int v2 = 0; v2 < 4; ++v2) {
        int row = v2 * 8 + (lane >> 3);
        int c8 = (lane & 7) * 8;
        u16x8 vec = *(const u16x8*)(ep + row * 72 + c8);
        long grow = bm + wm + half * 32 + row;
        int gcol = (int)bnn + wn + c8;
        if (gcol < Nreal) *(u16x8*)((u16*)C + grow * (long)ldc + gcol) = vec;
      }
      __syncthreads();
    }
  }
}

// ---------------- top-8 per row, parallel tree merge ----------------
DEV bool better(float v1, int i1, float v2, int i2) {
  return v1 > v2 || (v1 == v2 && i1 < i2);
}
__global__ __launch_bounds__(256) void topk_kernel(const float* __restrict__ sim,
                                                   int* __restrict__ idxout) {
  const int bn = blockIdx.x;
  const int tid = threadIdx.x;
  const float* row = sim + (long)bn * 8192;
  float bv[8]; int bi[8];
#pragma unroll
  for (int r = 0; r < 8; ++r) { bv[r] = -3.0e38f; bi[r] = 0x7fffffff; }
  for (int n = tid; n < 8192; n += 256) {
    float v = row[n];
    if (better(v, n, bv[7], bi[7])) {
      bv[7] = v; bi[7] = n;
      for (int r = 7; r > 0; --r) {
        if (!better(bv[r], bi[r], bv[r - 1], bi[r - 1])) break;
        float tv = bv[r]; bv[r] = bv[r - 1]; bv[r - 1] = tv;
        int ti = bi[r]; bi[r] = bi[r - 1]; bi[r - 1] = ti;
      }
    }
  }
  __shared__ float lv[256 * 8];
  __shared__ int li[256 * 8];
#pragma unroll
  for (int r = 0; r < 8; ++r) { lv[tid * 8 + r] = bv[r]; li[tid * 8 + r] = bi[r]; }
  __syncthreads();
  for (int step = 128; step >= 1; step >>= 1) {
    if (tid < step) {
      float av[8], xv[8]; int ai[8], xi[8];
#pragma unroll
      for (int r = 0; r < 8; ++r) {
        av[r] = lv[tid * 8 + r]; ai[r] = li[tid * 8 + r];
        xv[r] = lv[(tid + step) * 8 + r]; xi[r] = li[(tid + step) * 8 + r];
      }
      int ia = 0, ib = 0;
      float mv[8]; int mi[8];
#pragma unroll
      for (int r = 0; r < 8; ++r) {
        if (better(av[ia], ai[ia], xv[ib], xi[ib])) { mv[r] = av[ia]; mi[r] = ai[ia]; ++ia; }
        else { mv[r] = xv[ib]; mi[r] = xi[ib]; ++ib; }
      }
#pragma unroll
      for (int r = 0; r < 8; ++r) { lv[tid * 8 + r] = mv[r]; li[tid * 8 + r] = mi[r]; }
    }
    __syncthreads();
  }
  if (tid < 8) idxout[bn * 8 + tid] = li[tid];
}

// ---------------- gather retrieved rows, f32 -> bf16, clamped (vectorized) ------
__global__ __launch_bounds__(256) void gather_kernel(const float* __restrict__ mb,
                                                     const int* __restrict__ idx,
                                                     u16* __restrict__ retrB) {
  int t = blockIdx.x * 256 + threadIdx.x;  // < 524288
  int m = t >> 6;
  int c8 = (t & 63) * 8;
  long r = idx[m];
  if (r < 0) r = 0;
  if (r > 8191) r = 8191;
  const float* src = mb + r * 512 + c8;
  u16x8 o;
#pragma unroll
  for (int z = 0; z < 8; ++z) o[z] = f2bf(src[z]);
  *(u16x8*)(retrB + (long)m * 512 + c8) = o;
}

// ---------------- mean over K of gelu-hidden -> bf16 (vectorized x8) ------------
__global__ __launch_bounds__(256) void gmean_kernel(const u16* __restrict__ hid,
                                                    u16* __restrict__ gmeanB) {
  int t = blockIdx.x * 256 + threadIdx.x;  // < 131072
  int bn = t >> 7, j8 = (t & 127) * 8;
  float s[8] = {};
#pragma unroll
  for (int k = 0; k < 8; ++k) {
    u16x8 v = *(const u16x8*)(hid + (long)(bn * 8 + k) * 1024 + j8);
#pragma unroll
    for (int z = 0; z < 8; ++z) s[z] += bf2f(v[z]);
  }
  u16x8 o;
#pragma unroll
  for (int z = 0; z < 8; ++z) o[z] = f2bf(s[z] * 0.125f);
  *(u16x8*)(gmeanB + (long)bn * 1024 + j8) = o;
}

// ---------------- MFMA attention; O -> contiguous obuf ---------------------------
__global__ __launch_bounds__(256) void attn_kernel(const u16* __restrict__ qkvb,
                                                   u16* __restrict__ obuf) {
  __shared__ __align__(16) u16 smem[26752];
  u16* Qs = smem;
  u16* Ks = smem + 8704;
  float* ss = (float*)(smem + 8704);   // overlay Ks
  u16* ps = smem;                      // overlay Qs
  u16* Os = smem;                      // overlay Qs/ps after PV operand loads
  u16* Vb = smem + 17408;
  float* red = (float*)(smem + 25728);
  const int bn = blockIdx.x, h = blockIdx.y;
  const int tid = threadIdx.x;
  const int lane = tid & 63, w = tid >> 6;
  const int r16 = lane & 15, q4 = lane >> 4;
  const long base = (long)bn * 64 * 1536 + h * 128;

  for (int c = tid; c < 1024; c += 256) {
    int r = c >> 4, c8 = (c & 15) * 8;
    u16x8 vq = *(const u16x8*)(qkvb + base + (long)r * 1536 + c8);
    u16x8 vk = *(const u16x8*)(qkvb + base + (long)r * 1536 + 512 + c8);
    u16x8 vv = *(const u16x8*)(qkvb + base + (long)r * 1536 + 1024 + c8);
    *(u16x8*)(Qs + r * 136 + c8) = vq;
    *(u16x8*)(Ks + r * 136 + c8) = vk;
    int kt = r >> 5, q4t = (r >> 3) & 3, e = r & 7;
    int nt = c8 >> 4, rb = c8 & 15;
    int vbase = (nt * 2 + kt) * 520 + (q4t * 16 + rb) * 8 + e;
#pragma unroll
    for (int z = 0; z < 8; ++z) Vb[vbase + z * 8] = vv[z];
  }
  __syncthreads();

  const int m0 = w * 16;
  f32x4 accS[4] = {};
#pragma unroll
  for (int k0 = 0; k0 < 128; k0 += 32) {
    bf16x8 av = *(const bf16x8*)(Qs + (m0 + r16) * 136 + k0 + q4 * 8);
#pragma unroll
    for (int j = 0; j < 4; ++j) {
      bf16x8 bvf = *(const bf16x8*)(Ks + (j * 16 + r16) * 136 + k0 + q4 * 8);
      accS[j] = __builtin_amdgcn_mfma_f32_16x16x32_bf16(av, bvf, accS[j], 0, 0, 0);
    }
  }
  __syncthreads();
  const float scale = 0.08838834764831845f;  // 1/sqrt(128)
#pragma unroll
  for (int j = 0; j < 4; ++j)
#pragma unroll
    for (int r = 0; r < 4; ++r)
      ss[(m0 + q4 * 4 + r) * 66 + j * 16 + r16] = accS[j][r] * scale;
  __syncthreads();

  {
    int r = tid >> 2, p = tid & 3;
    float* row = ss + r * 66 + p * 16;
    float mx = -3.0e38f;
#pragma unroll
    for (int c2 = 0; c2 < 16; ++c2) mx = fmaxf(mx, row[c2]);
    red[r * 4 + p] = mx;
    __syncthreads();
    float m4 = fmaxf(fmaxf(red[r * 4], red[r * 4 + 1]),
                     fmaxf(red[r * 4 + 2], red[r * 4 + 3]));
    float s = 0.f;
#pragma unroll
    for (int c2 = 0; c2 < 16; ++c2) {
      float e = expf(row[c2] - m4);
      row[c2] = e;
      s += e;
    }
    red[256 + r * 4 + p] = s;
    __syncthreads();
    float inv = 1.f / (red[256 + r * 4] + red[256 + r * 4 + 1] +
                       red[256 + r * 4 + 2] + red[256 + r * 4 + 3]);
    u16x8 o0, o1;
#pragma unroll
    for (int z = 0; z < 8; ++z) {
      o0[z] = f2bf(row[z] * inv);
      o1[z] = f2bf(row[8 + z] * inv);
    }
    *(u16x8*)(ps + r * 72 + p * 16) = o0;
    *(u16x8*)(ps + r * 72 + p * 16 + 8) = o1;
  }
  __syncthreads();

  bf16x8 av0 = *(const bf16x8*)(ps + (m0 + r16) * 72 + q4 * 8);
  bf16x8 av1 = *(const bf16x8*)(ps + (m0 + r16) * 72 + 32 + q4 * 8);
  __syncthreads();  // everyone done reading ps before Os overwrites it
#pragma unroll
  for (int nt = 0; nt < 8; ++nt) {
    f32x4 accO = {};
    bf16x8 bv0 = *(const bf16x8*)(Vb + (nt * 2 + 0) * 520 + lane * 8);
    bf16x8 bv1 = *(const bf16x8*)(Vb + (nt * 2 + 1) * 520 + lane * 8);
    accO = __builtin_amdgcn_mfma_f32_16x16x32_bf16(av0, bv0, accO, 0, 0, 0);
    accO = __builtin_amdgcn_mfma_f32_16x16x32_bf16(av1, bv1, accO, 0, 0, 0);
#pragma unroll
    for (int r = 0; r < 4; ++r) {
      int i = m0 + q4 * 4 + r;
      int col = nt * 16 + r16;
      Os[i * 128 + (col ^ (q4 << 4))] = f2bf(accO[r]);
    }
  }
  __syncthreads();
  // coalesced store: O rows -> obuf [65536 x 512], head h at cols h*128..h*128+127
#pragma unroll
  for (int z = 0; z < 4; ++z) {
    int idx = z * 256 + tid;
    int row = idx >> 4, c8 = (idx & 15) * 8;
    int c8s = c8 ^ (((row >> 2) & 3) << 4);
    u16x8 vec = *(const u16x8*)(Os + row * 128 + c8s);
    *(u16x8*)(obuf + ((long)bn * 64 + row) * 512 + h * 128 + c8) = vec;
  }
}

// ---------------- local = emb + hmean -> locglob cols 0-511 (vectorized x8) -----
__global__ __launch_bounds__(256) void local_kernel(const u16* __restrict__ embh,
                                                    const u16* __restrict__ hmeanB,
                                                    u16* __restrict__ locglob) {
  long t = (long)blockIdx.x * 256 + threadIdx.x;  // < 4194304
  long e8 = t * 8;
  long m = e8 >> 9;
  int d = (int)(e8 & 511);
  int bn = (int)(m >> 6);
  u16x8 a = *(const u16x8*)(embh + e8);
  u16x8 b = *(const u16x8*)(hmeanB + (long)bn * 512 + d);
  u16x8 o;
#pragma unroll
  for (int z = 0; z < 8; ++z) o[z] = f2bf(bf2f(a[z]) + bf2f(b[z]));
  *(u16x8*)(locglob + m * 1024 + d) = o;
}

// ---------------- mem = softmax-gate combine -> embh (vector x8) ----------------
__global__ __launch_bounds__(256) void memc_kernel(u16* __restrict__ embh,
                                                   const u16* __restrict__ locglob,
                                                   const float* __restrict__ gatel,
                                                   const float* __restrict__ b_g2) {
  long t = (long)blockIdx.x * 256 + threadIdx.x;  // < 4194304
  long e8 = t * 8;
  long m = e8 >> 9;
  int d = (int)(e8 & 511);
  float l0 = gatel[m * 2] + b_g2[0];
  float l1 = gatel[m * 2 + 1] + b_g2[1];
  float mx = fmaxf(l0, l1);
  float e0 = expf(l0 - mx), e1 = expf(l1 - mx);
  float inv = 1.f / (e0 + e1);
  float g0 = e0 * inv, g1 = e1 * inv;
  u16x8 loc = *(const u16x8*)(locglob + m * 1024 + d);
  u16x8 gl = *(const u16x8*)(locglob + m * 1024 + 512 + d);
  u16x8 o;
#pragma unroll
  for (int z = 0; z < 8; ++z) o[z] = f2bf(g0 * bf2f(loc[z]) + g1 * bf2f(gl[z]));
  *(u16x8*)(embh + e8) = o;
}

// ---------------- fusion head + denorm + transpose store (f32) ----------------
// mh16: 16 split-K slices of [1024,192]; summed here (replaces global atomics)
__global__ __launch_bounds__(256) void fusion_kernel(const float* __restrict__ mh16,
                                                     const float* __restrict__ b_h,
                                                     const float* __restrict__ W_f1,
                                                     const float* __restrict__ b_f1,
                                                     const float* __restrict__ W_f2,
                                                     const float* __restrict__ b_f2,
                                                     const float* __restrict__ meanv,
                                                     const float* __restrict__ stdv,
                                                     float* __restrict__ out) {
  int bn = blockIdx.x;
  int tid = threadIdx.x;
  __shared__ float mrow[192];
  __shared__ float h1[384];
  if (tid < 192) {
    float a = b_h[tid];
#pragma unroll
    for (int z = 0; z < 16; ++z) a += mh16[(long)z * 196608 + (long)bn * 192 + tid];
    mrow[tid] = a;
  }
  __syncthreads();
  for (int j = tid; j < 384; j += 256) {
    float a = b_f1[j];
    for (int i = 0; i < 192; ++i) a += mrow[i] * W_f1[i * 384 + j];
    h1[j] = gelu_f(a);
  }
  __syncthreads();
  if (tid < 192) {
    float a = b_f2[tid];
    for (int j = 0; j < 384; ++j) a += h1[j] * W_f2[j * 192 + tid];
    float o = gelu_f(a) + mrow[tid];
    int b = bn >> 6, v = bn & 63;
    out[((long)b * 192 + tid) * 64 + v] = o * stdv[bn] + meanv[bn];
  }
}

extern "C" void kernel_launch(void* const* d_in, const int* in_sizes, int n_in,
                              void* d_out, int out_size, void* d_ws, size_t ws_size,
                              hipStream_t stream) {
  (void)in_sizes; (void)n_in; (void)out_size; (void)d_ws; (void)ws_size;
  const float* x_enc = (const float*)d_in[0];
  const float* W_val = (const float*)d_in[1];
  const float* mem_bank = (const float*)d_in[2];
  const float* W_m1 = (const float*)d_in[3];
  const float* b_m1 = (const float*)d_in[4];
  const float* W_m2 = (const float*)d_in[5];
  const float* b_m2 = (const float*)d_in[6];
  const float* W_q = (const float*)d_in[7];
  const float* b_q = (const float*)d_in[8];
  const float* W_k = (const float*)d_in[9];
  const float* b_k = (const float*)d_in[10];
  const float* W_v = (const float*)d_in[11];
  const float* b_v = (const float*)d_in[12];
  const float* W_o = (const float*)d_in[13];
  const float* b_o = (const float*)d_in[14];
  const float* W_g1 = (const float*)d_in[15];
  const float* b_g1 = (const float*)d_in[16];
  const float* W_g2 = (const float*)d_in[17];
  const float* b_g2 = (const float*)d_in[18];
  const float* W_h = (const float*)d_in[19];
  const float* b_h = (const float*)d_in[20];
  const float* W_f1 = (const float*)d_in[21];
  const float* b_f1 = (const float*)d_in[22];
  const float* W_f2 = (const float*)d_in[23];
  const float* b_f2 = (const float*)d_in[24];

  void* sp = nullptr;
  hipGetSymbolAddress(&sp, HIP_SYMBOL(g_s));
  Scratch* S = (Scratch*)sp;
  // sim-phase aliases inside qkvb (all dead before fused QKV writes it)
  float* simB = (float*)S->qkvb;                            // 32 MB
  u16* qsC = S->qkvb + (size_t)16 * 1024 * 1024;            // 3 MB
  u16* retrB = S->qkvb + (size_t)18 * 1024 * 1024;          // 8 MB
  u16* hiddenB = S->qkvb + (size_t)24 * 1024 * 1024;        // 16 MB
  // mh split-K slices alias qkvb too (dead after memc, fully rewritten next iter)
  float* mh16 = (float*)S->qkvb;                            // 12.6 MB

  // allow 96 KB dynamic LDS for the big-tile GEMM (no-op if already set)
  hipFuncSetAttribute(reinterpret_cast<const void*>(&gemm_db2<0>),
                      hipFuncAttributeMaxDynamicSharedMemorySize, 98304);
  hipFuncSetAttribute(reinterpret_cast<const void*>(&gemm_db2<4>),
                      hipFuncAttributeMaxDynamicSharedMemorySize, 98304);

  // setup
  pos_kernel<<<64, 256, 0, stream>>>(S->POSb);
  stats_kernel<<<16, 256, 0, stream>>>(x_enc, S->meanv, S->stdv);
  zerof_kernel<<<512, 256, 0, stream>>>(S->gatel, 65536 * 2);
  zerou8_kernel<<<1024, 256, 0, stream>>>(S->WhT + (size_t)192 * 32768, 64 * 32768 / 8);
  biasqkv_kernel<<<6, 256, 0, stream>>>(b_q, b_k, b_v, S->bqkv);
  transpose_kernel<<<dim3(16, 16), 256, 0, stream>>>(W_q, S->WqkvT, 512, 512);
  transpose_kernel<<<dim3(16, 16), 256, 0, stream>>>(W_k, S->WqkvT + 512 * 512, 512, 512);
  transpose_kernel<<<dim3(16, 16), 256, 0, stream>>>(W_v, S->WqkvT + 2 * 512 * 512, 512, 512);
  transpose_kernel<<<dim3(16, 16), 256, 0, stream>>>(W_o, S->WoT, 512, 512);
  transpose_kernel<<<dim3(32, 16), 256, 0, stream>>>(W_m1, S->Wm1T, 512, 1024);
  transpose_kernel<<<dim3(16, 32), 256, 0, stream>>>(W_m2, S->Wm2T, 1024, 512);
  transpose_kernel<<<dim3(16, 32), 256, 0, stream>>>(W_g1, S->Wg1T, 1024, 512);
  transpose_kernel<<<dim3(6, 1024), 256, 0, stream>>>(W_h, S->WhT, 32768, 192);
  memdup_kernel<<<2048, 256, 0, stream>>>(mem_bank, S->memdupB);

  // embedding (writes embh + fused [qh|ql|qh] sim-query rows)
  emb_kernel<<<1024, 256, 0, stream>>>(x_enc, W_val, S->POSb, S->meanv, S->stdv,
                                       S->embh, qsC);
  // retrieval sim: Mtiles=8, nT=64 -> grid 512
  gemm_db<3><<<512, 256, 0, stream>>>(qsC, S->memdupB, nullptr, simB, nullptr, nullptr,
                                      1536, 1536, 1536, 8192, 8192, 64, 0L);
  topk_kernel<<<1024, 256, 0, stream>>>(simB, S->idxB);
  gather_kernel<<<2048, 256, 0, stream>>>(mem_bank, S->idxB, retrB);
  // Wm1: Mtiles=64, nT=8 -> grid 512
  gemm_db<1><<<512, 256, 0, stream>>>(retrB, S->Wm1T, b_m1, hiddenB, nullptr, nullptr,
                                      512, 512, 512, 1024, 1024, 8, 0L);
  gmean_kernel<<<512, 256, 0, stream>>>(hiddenB, S->gmeanB);
  // hmean: Mtiles=8, nT=4 -> grid 32
  gemm_db<0><<<32, 256, 0, stream>>>(S->gmeanB, S->Wm2T, b_m2, S->hmeanB, nullptr, nullptr,
                                     1024, 1024, 1024, 512, 512, 4, 0L);
  // fused QKV: big-tile (BM=256) Mtiles=256, nT=12 -> grid 3072, 512 thr, 96KB dyn LDS
  gemm_db2<0><<<3072, 512, 98304, stream>>>(S->embh, S->WqkvT, S->bqkv, S->qkvb,
                                            nullptr, nullptr,
                                            512, 512, 512, 1536, 1536, 12);
  // local = emb + hmean -> locglob[:, 0:512]
  local_kernel<<<16384, 256, 0, stream>>>(S->embh, S->hmeanB, S->locglob);
  // attention: O -> contiguous obuf
  attn_kernel<<<dim3(1024, 4), 256, 0, stream>>>(S->qkvb, S->obuf);
  // glob = O @ W_o + b_o -> locglob[:, 512:1024] (big-tile: Mtiles=256, nT=4)
  gemm_db2<0><<<1024, 512, 98304, stream>>>(S->obuf, S->WoT, b_o, S->locglob + 512,
                                            nullptr, nullptr,
                                            512, 512, 512, 512, 1024, 4);
  // gate logits: big-tile K=1024 GEMM + fused gate epilogue
  gemm_db2<4><<<1024, 512, 98304, stream>>>(S->locglob, S->Wg1T, b_g1, nullptr,
                                            W_g2, S->gatel, 1024, 1024, 1024, 512, 0, 4);
  // mem = softmax(gate)-combine of locglob halves -> embh
  memc_kernel<<<16384, 256, 0, stream>>>(S->embh, S->locglob, S->gatel, b_g2);
  // mh = mem_flat [1024,32768] @ WhT^T, split-K z=16 (K=2048/slice) -> f32 slices
  gemm_db<3><<<dim3(16, 1, 16), 256, 0, stream>>>(S->embh, S->WhT, nullptr, mh16,
                                                  nullptr, nullptr,
                                                  32768, 32768, 2048, 192, 192, 2,
                                                  196608L);
  fusion_kernel<<<1024, 256, 0, stream>>>(mh16, b_h, W_f1, b_f1, W_f2, b_f2,
                                          S->meanv, S->stdv, (float*)d_out);
}

// Round 9
// 928.209 us; speedup vs baseline: 1.0927x; 1.0567x over previous
//
#include <hip/hip_runtime.h>
#include <stdint.h>

#define DEV __device__ __forceinline__

typedef uint16_t u16;
typedef __bf16 bf16x8 __attribute__((ext_vector_type(8)));
typedef float f32x4 __attribute__((ext_vector_type(4)));
typedef u16 u16x8 __attribute__((ext_vector_type(8)));

DEV float bf2f(u16 v) { return __uint_as_float(((uint32_t)v) << 16); }
DEV u16 f2bf(float f) {
  uint32_t u = __float_as_uint(f);
  u += 0x7fffu + ((u >> 16) & 1u);
  return (u16)(u >> 16);
}
DEV float gelu_f(float x) { return 0.5f * x * (1.0f + erff(x * 0.7071067811865475f)); }

DEV void gload_lds16(const u16* g, u16* l) {
  __builtin_amdgcn_global_load_lds(
      (const __attribute__((address_space(1))) void*)g,
      (__attribute__((address_space(3))) void*)l, 16, 0, 0);
}

// ---- all scratch in a static device global (R4: never trust ws_size) ----
struct __align__(16) Scratch {
  float POSb[64 * 512];
  float meanv[1024];
  float stdv[1024];
  float mh[1024 * 192];
  int idxB[8192];
  float qflat[1024 * 512];
  float gatel[65536 * 2];
  float bqkv[1536];
  u16 hmeanB[1024 * 512];
  u16 gmeanB[1024 * 1024];
  u16 WqkvT[1536 * 512];       // rows 0-511 Wq^T, 512-1023 Wk^T, 1024-1535 Wv^T
  u16 WoT[512 * 512];
  u16 Wm1T[1024 * 512];
  u16 Wm2T[512 * 1024];
  u16 Wg1T[512 * 1024];
  u16 WhT[256 * 32768];        // rows 192..255 zero-filled
  u16 memdupB[8192 * 1536];    // [mh|mh|ml] 24 MB
  u16 embh[65536 * 512];       // 64 MB: emb -> mem (memc result, feeds mh)
  u16 locglob[65536 * 1024];   // 128 MB: [local | glob] contiguous rows
  u16 obuf[65536 * 512];       // 64 MB: attention O, contiguous
  u16 qkvb[65536 * 1536];      // 192 MB: Q|K|V (sim aliases + mh slices live here)
};
__device__ Scratch g_s;

// ---------------- fills / small setup ----------------
__global__ __launch_bounds__(256) void zerof_kernel(float* __restrict__ p, int n) {
  int t = blockIdx.x * 256 + threadIdx.x;
  if (t < n) p[t] = 0.f;
}
__global__ __launch_bounds__(256) void zerou8_kernel(u16* __restrict__ p, int n8) {
  int t = blockIdx.x * 256 + threadIdx.x;
  if (t < n8) *(u16x8*)(p + (long)t * 8) = (u16x8)0;
}
__global__ __launch_bounds__(256) void biasqkv_kernel(const float* __restrict__ bq,
                                                      const float* __restrict__ bk,
                                                      const float* __restrict__ bv,
                                                      float* __restrict__ o) {
  int t = blockIdx.x * 256 + threadIdx.x;  // < 1536
  o[t] = t < 512 ? bq[t] : (t < 1024 ? bk[t - 512] : bv[t - 1024]);
}

// ---------------- POS embedding ----------------
__global__ __launch_bounds__(256) void pos_kernel(float* __restrict__ POS) {
  int n = blockIdx.x;
  int i = threadIdx.x;
  float div = expf((float)(2 * i) * (-9.210340371976184f / 512.0f));
  float arg = (float)n * div;
  POS[n * 512 + 2 * i] = sinf(arg);
  POS[n * 512 + 2 * i + 1] = cosf(arg);
}

// ---------------- instance-norm stats ----------------
__global__ __launch_bounds__(256) void stats_kernel(const float* __restrict__ x_enc,
                                                    float* __restrict__ meanv,
                                                    float* __restrict__ stdv) {
  int b = blockIdx.x;
  int v = threadIdx.x & 63;
  int g = threadIdx.x >> 6;
  float s = 0.f, s2 = 0.f;
  for (int l = g; l < 512; l += 4) {
    float x = x_enc[((long)b * 512 + l) * 64 + v];
    s += x; s2 += x * x;
  }
  __shared__ float sh[2][4][64];
  sh[0][g][v] = s; sh[1][g][v] = s2;
  __syncthreads();
  if (g == 0) {
    s = sh[0][0][v] + sh[0][1][v] + sh[0][2][v] + sh[0][3][v];
    s2 = sh[1][0][v] + sh[1][1][v] + sh[1][2][v] + sh[1][3][v];
    float mu = s * (1.f / 512.f);
    float var = s2 * (1.f / 512.f) - mu * mu;
    meanv[b * 64 + v] = mu;
    stdv[b * 64 + v] = sqrtf(var + 1e-5f) * 2.5f;  // sqrt(var+eps)/0.4
  }
}

// ---------------- transpose f32 [R,C] -> bf16 [C,R] ----------------
__global__ __launch_bounds__(256) void transpose_kernel(const float* __restrict__ in,
                                                        u16* __restrict__ out, int R, int C) {
  __shared__ u16 t[32][33];
  int bx = blockIdx.x * 32;
  int by = blockIdx.y * 32;
  int tx = threadIdx.x & 31, ty = threadIdx.x >> 5;
  for (int i = ty; i < 32; i += 8) t[i][tx] = f2bf(in[(long)(by + i) * C + bx + tx]);
  __syncthreads();
  for (int i = ty; i < 32; i += 8) out[(long)(bx + i) * R + by + tx] = t[tx][i];
}

// ---------------- patch embed + fused qflat->[qh|ql|qh] row ----------------
__global__ __launch_bounds__(256) void emb_kernel(const float* __restrict__ x_enc,
                                                  const float* __restrict__ W_val,
                                                  const float* __restrict__ POS,
                                                  const float* __restrict__ meanv,
                                                  const float* __restrict__ stdv,
                                                  u16* __restrict__ embh,
                                                  u16* __restrict__ qsC) {
  int bn = blockIdx.x;
  int b = bn >> 6, v = bn & 63;
  int tid = threadIdx.x;
  __shared__ __align__(16) float wv[16 * 512];
  __shared__ __align__(16) float pt[64 * 16];
  for (int i = tid; i < 8192; i += 256) wv[i] = W_val[i];
  float mu = meanv[bn];
  float inv = 1.f / stdv[bn];
  for (int i = tid; i < 1024; i += 256) {
    int n = i >> 4, p = i & 15;
    int l = n * 8 + p; if (l > 511) l = 511;  // replication pad
    pt[i] = (x_enc[((long)b * 512 + l) * 64 + v] - mu) * inv;
  }
  __syncthreads();
  float qs0 = 0.f, qs1 = 0.f;
  int d0 = tid, d1 = tid + 256;
  for (int n = 0; n < 64; ++n) {
    float a0 = POS[n * 512 + d0], a1 = POS[n * 512 + d1];
#pragma unroll
    for (int p = 0; p < 16; ++p) {
      float pv = pt[n * 16 + p];
      a0 += pv * wv[p * 512 + d0];
      a1 += pv * wv[p * 512 + d1];
    }
    long base = ((long)bn * 64 + n) * 512;
    embh[base + d0] = f2bf(a0);
    embh[base + d1] = f2bf(a1);
    qs0 += a0; qs1 += a1;
  }
  float q0 = qs0 * (1.f / 64.f), q1 = qs1 * (1.f / 64.f);
  u16 h0 = f2bf(q0), l0 = f2bf(q0 - bf2f(h0));
  u16 h1 = f2bf(q1), l1 = f2bf(q1 - bf2f(h1));
  long qb = (long)bn * 1536;
  qsC[qb + d0] = h0; qsC[qb + 512 + d0] = l0; qsC[qb + 1024 + d0] = h0;
  qsC[qb + d1] = h1; qsC[qb + 512 + d1] = l1; qsC[qb + 1024 + d1] = h1;
}

// ---------------- mem_bank f32 -> [mh|mh|ml] bf16 row of 1536 (vectorized x8) ---
__global__ __launch_bounds__(256) void memdup_kernel(const float* __restrict__ mb,
                                                     u16* __restrict__ md) {
  int t = blockIdx.x * 256 + threadIdx.x;  // < 524288
  int n = t >> 6, k8 = (t & 63) * 8;
  const float* src = mb + (long)n * 512 + k8;
  u16x8 hi, lo;
#pragma unroll
  for (int z = 0; z < 8; ++z) {
    float m = src[z];
    u16 h = f2bf(m);
    hi[z] = h;
    lo[z] = f2bf(m - bf2f(h));
  }
  long base = (long)n * 1536 + k8;
  *(u16x8*)(md + base) = hi;
  *(u16x8*)(md + base + 512) = hi;
  *(u16x8*)(md + base + 1024) = lo;
}

// ---------------- double-buffered NT GEMM (T3 minimum 2-phase, counted vmcnt) -----
// Unified GEMM for ALL shapes (proven structure from round 5/6).
// Prefetch tile s+1 is issued BEFORE computing tile s; s_waitcnt vmcnt(8) leaves
// the prefetch's 8 loads in flight across the barrier. Raw s_barrier (no drain)
// + sched_barrier fences. Buffer written at s is read at s; re-staged only after
// the post-MFMA barrier -> no write-while-read hazard.
// EPI: 0 bias+bf16 | 1 bias+gelu+bf16 | 3 f32 store (z-sliced via zstride)
//      4 fused gate-logit epilogue (h1=gelu(acc+b); dot W_g2 -> atomics)
// blockIdx.z selects the K-slice (koff) AND the output slice (EPI 3).
template <int EPI>
__global__ __launch_bounds__(256) void gemm_db(const u16* __restrict__ Ag,
                                               const u16* __restrict__ Bt,
                                               const float* __restrict__ bias,
                                               void* __restrict__ C,
                                               const float* __restrict__ W_g2,
                                               float* __restrict__ gatel,
                                               int lda, int ldb, int K, int Nreal, int ldc,
                                               int nT, long zstride) {
  __shared__ __align__(16) u16 smem[4 * 128 * 64];  // 64 KB: 2 x (As 16K + Bs 16K)
  const int tid = threadIdx.x;
  const int id = blockIdx.x;
  const int xcd = id & 7;
  const int kk = id >> 3;
  const long bm = (long)((kk / nT) * 8 + xcd) * 128;
  const long bnn = (long)(kk % nT) * 128;
  const long koff = (long)blockIdx.z * (long)K;
  const int lane = tid & 63;
  const int w = tid >> 6;
  const int wm = (w & 1) * 64;
  const int wn = (w >> 1) * 64;
  const int r16 = lane & 15;
  const int q4 = lane >> 4;

  f32x4 acc[4][4] = {};

  const u16* ap[4];
  const u16* bp[4];
  int ao[4], bo[4];
#pragma unroll
  for (int j = 0; j < 4; ++j) {
    int cid = (j * 4 + w) * 64 + lane;
    int r = cid >> 3;
    int g = (cid & 7) ^ (r & 7);
    ap[j] = Ag + (bm + r) * lda + koff + g * 8;
    bp[j] = Bt + (bnn + r) * ldb + koff + g * 8;
    ao[j] = cid * 8;
    bo[j] = 8192 + cid * 8;
  }

  // prologue: stage buffer 0 (8 vmem ops/thread)
#pragma unroll
  for (int j = 0; j < 4; ++j) gload_lds16(ap[j], smem + ao[j]);
#pragma unroll
  for (int j = 0; j < 4; ++j) gload_lds16(bp[j], smem + bo[j]);

  const int nsteps = K >> 6;
  for (int s = 0; s < nsteps; ++s) {
    const int cur = s & 1;
    u16* buf = smem + cur * 16384;
    if (s + 1 < nsteps) {
      u16* nb = smem + (cur ^ 1) * 16384;
      const int k1 = (s + 1) << 6;
#pragma unroll
      for (int j = 0; j < 4; ++j) gload_lds16(ap[j] + k1, nb + ao[j]);
#pragma unroll
      for (int j = 0; j < 4; ++j) gload_lds16(bp[j] + k1, nb + bo[j]);
      asm volatile("s_waitcnt vmcnt(8)" ::: "memory");  // cur's 8 done; prefetch in flight
    } else {
      asm volatile("s_waitcnt vmcnt(0)" ::: "memory");
    }
    __builtin_amdgcn_sched_barrier(0);
    __builtin_amdgcn_s_barrier();
    __builtin_amdgcn_sched_barrier(0);
    u16* As = buf;
    u16* Bs = buf + 8192;
#pragma unroll
    for (int sub = 0; sub < 2; ++sub) {
      const int gg = q4 + sub * 4;
      bf16x8 av[4], bv[4];
#pragma unroll
      for (int i = 0; i < 4; ++i) {
        int r = wm + i * 16 + r16;
        av[i] = *reinterpret_cast<const bf16x8*>(As + (r * 8 + (gg ^ (r & 7))) * 8);
      }
#pragma unroll
      for (int j2 = 0; j2 < 4; ++j2) {
        int r = wn + j2 * 16 + r16;
        bv[j2] = *reinterpret_cast<const bf16x8*>(Bs + (r * 8 + (gg ^ (r & 7))) * 8);
      }
#pragma unroll
      for (int i = 0; i < 4; ++i)
#pragma unroll
        for (int j2 = 0; j2 < 4; ++j2)
          acc[i][j2] = __builtin_amdgcn_mfma_f32_16x16x32_bf16(av[i], bv[j2], acc[i][j2], 0, 0, 0);
    }
    __builtin_amdgcn_sched_barrier(0);
    __builtin_amdgcn_s_barrier();  // all reads of buf retired before restage
    __builtin_amdgcn_sched_barrier(0);
  }

  if (EPI == 3) {
    // f32 out: stage per-wave half-tiles -> f32x4 stores (smem free after last barrier)
    float* Cz = (float*)C + (long)blockIdx.z * zstride;
    float* epf = (float*)smem + w * 2048;
#pragma unroll
    for (int half = 0; half < 2; ++half) {
#pragma unroll
      for (int i = 0; i < 2; ++i)
#pragma unroll
        for (int j = 0; j < 4; ++j)
#pragma unroll
          for (int r = 0; r < 4; ++r)
            epf[(i * 16 + q4 * 4 + r) * 64 + j * 16 + r16] = acc[half * 2 + i][j][r];
      __syncthreads();
#pragma unroll
      for (int v2 = 0; v2 < 8; ++v2) {
        int idx = v2 * 64 + lane;
        int row = idx >> 4, c4 = (idx & 15) * 4;
        f32x4 vec = *(const f32x4*)(epf + row * 64 + c4);
        long grow = bm + wm + half * 32 + row;
        int gcol = (int)bnn + wn + c4;
        if (gcol < Nreal) *(f32x4*)(Cz + grow * (long)ldc + gcol) = vec;
      }
      __syncthreads();
    }
  } else if (EPI == 4) {
    // fused gate-head; per-row dot with W_g2 (2 cols), no h1 materialization
    float bcol[4], w0[4], w1[4];
#pragma unroll
    for (int j = 0; j < 4; ++j) {
      int gc = (int)bnn + wn + j * 16 + r16;
      bcol[j] = bias[gc];
      w0[j] = W_g2[gc * 2];
      w1[j] = W_g2[gc * 2 + 1];
    }
#pragma unroll
    for (int i = 0; i < 4; ++i)
#pragma unroll
      for (int r = 0; r < 4; ++r) {
        float a0 = 0.f, a1 = 0.f;
#pragma unroll
        for (int j = 0; j < 4; ++j) {
          float h = gelu_f(acc[i][j][r] + bcol[j]);
          a0 += h * w0[j];
          a1 += h * w1[j];
        }
#pragma unroll
        for (int off = 1; off < 16; off <<= 1) {
          a0 += __shfl_xor(a0, off);
          a1 += __shfl_xor(a1, off);
        }
        if (r16 == 0) {
          long row = bm + wm + i * 16 + q4 * 4 + r;
          atomicAdd(&gatel[row * 2], a0);
          atomicAdd(&gatel[row * 2 + 1], a1);
        }
      }
  } else {
    // bf16 out (+bias, optional gelu): two 32-row half-tiles, stride-72 staging
    u16* ep = smem + w * 2304;
    float bcol[4];
#pragma unroll
    for (int j = 0; j < 4; ++j) bcol[j] = bias[bnn + wn + j * 16 + r16];
#pragma unroll
    for (int half = 0; half < 2; ++half) {
#pragma unroll
      for (int i = 0; i < 2; ++i)
#pragma unroll
        for (int j = 0; j < 4; ++j)
#pragma unroll
          for (int r = 0; r < 4; ++r) {
            float v = acc[half * 2 + i][j][r] + bcol[j];
            if (EPI == 1) v = gelu_f(v);
            ep[(i * 16 + q4 * 4 + r) * 72 + j * 16 + r16] = f2bf(v);
          }
      __syncthreads();
#pragma unroll
      for (int v2 = 0; v2 < 4; ++v2) {
        int row = v2 * 8 + (lane >> 3);
        int c8 = (lane & 7) * 8;
        u16x8 vec = *(const u16x8*)(ep + row * 72 + c8);
        long grow = bm + wm + half * 32 + row;
        int gcol = (int)bnn + wn + c8;
        if (gcol < Nreal) *(u16x8*)((u16*)C + grow * (long)ldc + gcol) = vec;
      }
      __syncthreads();
    }
  }
}

// ---------------- top-8 per row, parallel tree merge ----------------
DEV bool better(float v1, int i1, float v2, int i2) {
  return v1 > v2 || (v1 == v2 && i1 < i2);
}
__global__ __launch_bounds__(256) void topk_kernel(const float* __restrict__ sim,
                                                   int* __restrict__ idxout) {
  const int bn = blockIdx.x;
  const int tid = threadIdx.x;
  const float* row = sim + (long)bn * 8192;
  float bv[8]; int bi[8];
#pragma unroll
  for (int r = 0; r < 8; ++r) { bv[r] = -3.0e38f; bi[r] = 0x7fffffff; }
  for (int n = tid; n < 8192; n += 256) {
    float v = row[n];
    if (better(v, n, bv[7], bi[7])) {
      bv[7] = v; bi[7] = n;
      for (int r = 7; r > 0; --r) {
        if (!better(bv[r], bi[r], bv[r - 1], bi[r - 1])) break;
        float tv = bv[r]; bv[r] = bv[r - 1]; bv[r - 1] = tv;
        int ti = bi[r]; bi[r] = bi[r - 1]; bi[r - 1] = ti;
      }
    }
  }
  __shared__ float lv[256 * 8];
  __shared__ int li[256 * 8];
#pragma unroll
  for (int r = 0; r < 8; ++r) { lv[tid * 8 + r] = bv[r]; li[tid * 8 + r] = bi[r]; }
  __syncthreads();
  for (int step = 128; step >= 1; step >>= 1) {
    if (tid < step) {
      float av[8], xv[8]; int ai[8], xi[8];
#pragma unroll
      for (int r = 0; r < 8; ++r) {
        av[r] = lv[tid * 8 + r]; ai[r] = li[tid * 8 + r];
        xv[r] = lv[(tid + step) * 8 + r]; xi[r] = li[(tid + step) * 8 + r];
      }
      int ia = 0, ib = 0;
      float mv[8]; int mi[8];
#pragma unroll
      for (int r = 0; r < 8; ++r) {
        if (better(av[ia], ai[ia], xv[ib], xi[ib])) { mv[r] = av[ia]; mi[r] = ai[ia]; ++ia; }
        else { mv[r] = xv[ib]; mi[r] = xi[ib]; ++ib; }
      }
#pragma unroll
      for (int r = 0; r < 8; ++r) { lv[tid * 8 + r] = mv[r]; li[tid * 8 + r] = mi[r]; }
    }
    __syncthreads();
  }
  if (tid < 8) idxout[bn * 8 + tid] = li[tid];
}

// ---------------- gather retrieved rows, f32 -> bf16, clamped (vectorized) ------
__global__ __launch_bounds__(256) void gather_kernel(const float* __restrict__ mb,
                                                     const int* __restrict__ idx,
                                                     u16* __restrict__ retrB) {
  int t = blockIdx.x * 256 + threadIdx.x;  // < 524288
  int m = t >> 6;
  int c8 = (t & 63) * 8;
  long r = idx[m];
  if (r < 0) r = 0;
  if (r > 8191) r = 8191;
  const float* src = mb + r * 512 + c8;
  u16x8 o;
#pragma unroll
  for (int z = 0; z < 8; ++z) o[z] = f2bf(src[z]);
  *(u16x8*)(retrB + (long)m * 512 + c8) = o;
}

// ---------------- mean over K of gelu-hidden -> bf16 (vectorized x8) ------------
__global__ __launch_bounds__(256) void gmean_kernel(const u16* __restrict__ hid,
                                                    u16* __restrict__ gmeanB) {
  int t = blockIdx.x * 256 + threadIdx.x;  // < 131072
  int bn = t >> 7, j8 = (t & 127) * 8;
  float s[8] = {};
#pragma unroll
  for (int k = 0; k < 8; ++k) {
    u16x8 v = *(const u16x8*)(hid + (long)(bn * 8 + k) * 1024 + j8);
#pragma unroll
    for (int z = 0; z < 8; ++z) s[z] += bf2f(v[z]);
  }
  u16x8 o;
#pragma unroll
  for (int z = 0; z < 8; ++z) o[z] = f2bf(s[z] * 0.125f);
  *(u16x8*)(gmeanB + (long)bn * 1024 + j8) = o;
}

// ---------------- MFMA attention; O -> contiguous obuf ---------------------------
__global__ __launch_bounds__(256) void attn_kernel(const u16* __restrict__ qkvb,
                                                   u16* __restrict__ obuf) {
  __shared__ __align__(16) u16 smem[26752];
  u16* Qs = smem;
  u16* Ks = smem + 8704;
  float* ss = (float*)(smem + 8704);   // overlay Ks
  u16* ps = smem;                      // overlay Qs
  u16* Os = smem;                      // overlay Qs/ps after PV operand loads
  u16* Vb = smem + 17408;
  float* red = (float*)(smem + 25728);
  const int bn = blockIdx.x, h = blockIdx.y;
  const int tid = threadIdx.x;
  const int lane = tid & 63, w = tid >> 6;
  const int r16 = lane & 15, q4 = lane >> 4;
  const long base = (long)bn * 64 * 1536 + h * 128;

  for (int c = tid; c < 1024; c += 256) {
    int r = c >> 4, c8 = (c & 15) * 8;
    u16x8 vq = *(const u16x8*)(qkvb + base + (long)r * 1536 + c8);
    u16x8 vk = *(const u16x8*)(qkvb + base + (long)r * 1536 + 512 + c8);
    u16x8 vv = *(const u16x8*)(qkvb + base + (long)r * 1536 + 1024 + c8);
    *(u16x8*)(Qs + r * 136 + c8) = vq;
    *(u16x8*)(Ks + r * 136 + c8) = vk;
    int kt = r >> 5, q4t = (r >> 3) & 3, e = r & 7;
    int nt = c8 >> 4, rb = c8 & 15;
    int vbase = (nt * 2 + kt) * 520 + (q4t * 16 + rb) * 8 + e;
#pragma unroll
    for (int z = 0; z < 8; ++z) Vb[vbase + z * 8] = vv[z];
  }
  __syncthreads();

  const int m0 = w * 16;
  f32x4 accS[4] = {};
#pragma unroll
  for (int k0 = 0; k0 < 128; k0 += 32) {
    bf16x8 av = *(const bf16x8*)(Qs + (m0 + r16) * 136 + k0 + q4 * 8);
#pragma unroll
    for (int j = 0; j < 4; ++j) {
      bf16x8 bvf = *(const bf16x8*)(Ks + (j * 16 + r16) * 136 + k0 + q4 * 8);
      accS[j] = __builtin_amdgcn_mfma_f32_16x16x32_bf16(av, bvf, accS[j], 0, 0, 0);
    }
  }
  __syncthreads();
  const float scale = 0.08838834764831845f;  // 1/sqrt(128)
#pragma unroll
  for (int j = 0; j < 4; ++j)
#pragma unroll
    for (int r = 0; r < 4; ++r)
      ss[(m0 + q4 * 4 + r) * 66 + j * 16 + r16] = accS[j][r] * scale;
  __syncthreads();

  {
    int r = tid >> 2, p = tid & 3;
    float* row = ss + r * 66 + p * 16;
    float mx = -3.0e38f;
#pragma unroll
    for (int c2 = 0; c2 < 16; ++c2) mx = fmaxf(mx, row[c2]);
    red[r * 4 + p] = mx;
    __syncthreads();
    float m4 = fmaxf(fmaxf(red[r * 4], red[r * 4 + 1]),
                     fmaxf(red[r * 4 + 2], red[r * 4 + 3]));
    float s = 0.f;
#pragma unroll
    for (int c2 = 0; c2 < 16; ++c2) {
      float e = expf(row[c2] - m4);
      row[c2] = e;
      s += e;
    }
    red[256 + r * 4 + p] = s;
    __syncthreads();
    float inv = 1.f / (red[256 + r * 4] + red[256 + r * 4 + 1] +
                       red[256 + r * 4 + 2] + red[256 + r * 4 + 3]);
    u16x8 o0, o1;
#pragma unroll
    for (int z = 0; z < 8; ++z) {
      o0[z] = f2bf(row[z] * inv);
      o1[z] = f2bf(row[8 + z] * inv);
    }
    *(u16x8*)(ps + r * 72 + p * 16) = o0;
    *(u16x8*)(ps + r * 72 + p * 16 + 8) = o1;
  }
  __syncthreads();

  bf16x8 av0 = *(const bf16x8*)(ps + (m0 + r16) * 72 + q4 * 8);
  bf16x8 av1 = *(const bf16x8*)(ps + (m0 + r16) * 72 + 32 + q4 * 8);
  __syncthreads();  // everyone done reading ps before Os overwrites it
#pragma unroll
  for (int nt = 0; nt < 8; ++nt) {
    f32x4 accO = {};
    bf16x8 bv0 = *(const bf16x8*)(Vb + (nt * 2 + 0) * 520 + lane * 8);
    bf16x8 bv1 = *(const bf16x8*)(Vb + (nt * 2 + 1) * 520 + lane * 8);
    accO = __builtin_amdgcn_mfma_f32_16x16x32_bf16(av0, bv0, accO, 0, 0, 0);
    accO = __builtin_amdgcn_mfma_f32_16x16x32_bf16(av1, bv1, accO, 0, 0, 0);
#pragma unroll
    for (int r = 0; r < 4; ++r) {
      int i = m0 + q4 * 4 + r;
      int col = nt * 16 + r16;
      Os[i * 128 + (col ^ (q4 << 4))] = f2bf(accO[r]);
    }
  }
  __syncthreads();
  // coalesced store: O rows -> obuf [65536 x 512], head h at cols h*128..h*128+127
#pragma unroll
  for (int z = 0; z < 4; ++z) {
    int idx = z * 256 + tid;
    int row = idx >> 4, c8 = (idx & 15) * 8;
    int c8s = c8 ^ (((row >> 2) & 3) << 4);
    u16x8 vec = *(const u16x8*)(Os + row * 128 + c8s);
    *(u16x8*)(obuf + ((long)bn * 64 + row) * 512 + h * 128 + c8) = vec;
  }
}

// ---------------- local = emb + hmean -> locglob cols 0-511 (vectorized x8) -----
__global__ __launch_bounds__(256) void local_kernel(const u16* __restrict__ embh,
                                                    const u16* __restrict__ hmeanB,
                                                    u16* __restrict__ locglob) {
  long t = (long)blockIdx.x * 256 + threadIdx.x;  // < 4194304
  long e8 = t * 8;
  long m = e8 >> 9;
  int d = (int)(e8 & 511);
  int bn = (int)(m >> 6);
  u16x8 a = *(const u16x8*)(embh + e8);
  u16x8 b = *(const u16x8*)(hmeanB + (long)bn * 512 + d);
  u16x8 o;
#pragma unroll
  for (int z = 0; z < 8; ++z) o[z] = f2bf(bf2f(a[z]) + bf2f(b[z]));
  *(u16x8*)(locglob + m * 1024 + d) = o;
}

// ---------------- mem = softmax-gate combine -> embh (vector x8) ----------------
__global__ __launch_bounds__(256) void memc_kernel(u16* __restrict__ embh,
                                                   const u16* __restrict__ locglob,
                                                   const float* __restrict__ gatel,
                                                   const float* __restrict__ b_g2) {
  long t = (long)blockIdx.x * 256 + threadIdx.x;  // < 4194304
  long e8 = t * 8;
  long m = e8 >> 9;
  int d = (int)(e8 & 511);
  float l0 = gatel[m * 2] + b_g2[0];
  float l1 = gatel[m * 2 + 1] + b_g2[1];
  float mx = fmaxf(l0, l1);
  float e0 = expf(l0 - mx), e1 = expf(l1 - mx);
  float inv = 1.f / (e0 + e1);
  float g0 = e0 * inv, g1 = e1 * inv;
  u16x8 loc = *(const u16x8*)(locglob + m * 1024 + d);
  u16x8 gl = *(const u16x8*)(locglob + m * 1024 + 512 + d);
  u16x8 o;
#pragma unroll
  for (int z = 0; z < 8; ++z) o[z] = f2bf(g0 * bf2f(loc[z]) + g1 * bf2f(gl[z]));
  *(u16x8*)(embh + e8) = o;
}

// ---------------- fusion head + denorm + transpose store (f32) ----------------
// mh32: 32 split-K slices of [1024,192]; summed here (replaces global atomics)
__global__ __launch_bounds__(256) void fusion_kernel(const float* __restrict__ mh32,
                                                     const float* __restrict__ b_h,
                                                     const float* __restrict__ W_f1,
                                                     const float* __restrict__ b_f1,
                                                     const float* __restrict__ W_f2,
                                                     const float* __restrict__ b_f2,
                                                     const float* __restrict__ meanv,
                                                     const float* __restrict__ stdv,
                                                     float* __restrict__ out) {
  int bn = blockIdx.x;
  int tid = threadIdx.x;
  __shared__ float mrow[192];
  __shared__ float h1[384];
  if (tid < 192) {
    float a = b_h[tid];
#pragma unroll
    for (int z = 0; z < 32; ++z) a += mh32[(long)z * 196608 + (long)bn * 192 + tid];
    mrow[tid] = a;
  }
  __syncthreads();
  for (int j = tid; j < 384; j += 256) {
    float a = b_f1[j];
    for (int i = 0; i < 192; ++i) a += mrow[i] * W_f1[i * 384 + j];
    h1[j] = gelu_f(a);
  }
  __syncthreads();
  if (tid < 192) {
    float a = b_f2[tid];
    for (int j = 0; j < 384; ++j) a += h1[j] * W_f2[j * 192 + tid];
    float o = gelu_f(a) + mrow[tid];
    int b = bn >> 6, v = bn & 63;
    out[((long)b * 192 + tid) * 64 + v] = o * stdv[bn] + meanv[bn];
  }
}

extern "C" void kernel_launch(void* const* d_in, const int* in_sizes, int n_in,
                              void* d_out, int out_size, void* d_ws, size_t ws_size,
                              hipStream_t stream) {
  (void)in_sizes; (void)n_in; (void)out_size; (void)d_ws; (void)ws_size;
  const float* x_enc = (const float*)d_in[0];
  const float* W_val = (const float*)d_in[1];
  const float* mem_bank = (const float*)d_in[2];
  const float* W_m1 = (const float*)d_in[3];
  const float* b_m1 = (const float*)d_in[4];
  const float* W_m2 = (const float*)d_in[5];
  const float* b_m2 = (const float*)d_in[6];
  const float* W_q = (const float*)d_in[7];
  const float* b_q = (const float*)d_in[8];
  const float* W_k = (const float*)d_in[9];
  const float* b_k = (const float*)d_in[10];
  const float* W_v = (const float*)d_in[11];
  const float* b_v = (const float*)d_in[12];
  const float* W_o = (const float*)d_in[13];
  const float* b_o = (const float*)d_in[14];
  const float* W_g1 = (const float*)d_in[15];
  const float* b_g1 = (const float*)d_in[16];
  const float* W_g2 = (const float*)d_in[17];
  const float* b_g2 = (const float*)d_in[18];
  const float* W_h = (const float*)d_in[19];
  const float* b_h = (const float*)d_in[20];
  const float* W_f1 = (const float*)d_in[21];
  const float* b_f1 = (const float*)d_in[22];
  const float* W_f2 = (const float*)d_in[23];
  const float* b_f2 = (const float*)d_in[24];

  void* sp = nullptr;
  hipGetSymbolAddress(&sp, HIP_SYMBOL(g_s));
  Scratch* S = (Scratch*)sp;
  // sim-phase aliases inside qkvb (all dead before fused QKV writes it)
  float* simB = (float*)S->qkvb;                            // 32 MB
  u16* qsC = S->qkvb + (size_t)16 * 1024 * 1024;            // 3 MB
  u16* retrB = S->qkvb + (size_t)18 * 1024 * 1024;          // 8 MB
  u16* hiddenB = S->qkvb + (size_t)24 * 1024 * 1024;        // 16 MB
  // mh split-K slices alias qkvb too (dead after memc, fully rewritten next iter)
  float* mh32 = (float*)S->qkvb;                            // 25 MB

  // setup
  pos_kernel<<<64, 256, 0, stream>>>(S->POSb);
  stats_kernel<<<16, 256, 0, stream>>>(x_enc, S->meanv, S->stdv);
  zerof_kernel<<<512, 256, 0, stream>>>(S->gatel, 65536 * 2);
  zerou8_kernel<<<1024, 256, 0, stream>>>(S->WhT + (size_t)192 * 32768, 64 * 32768 / 8);
  biasqkv_kernel<<<6, 256, 0, stream>>>(b_q, b_k, b_v, S->bqkv);
  transpose_kernel<<<dim3(16, 16), 256, 0, stream>>>(W_q, S->WqkvT, 512, 512);
  transpose_kernel<<<dim3(16, 16), 256, 0, stream>>>(W_k, S->WqkvT + 512 * 512, 512, 512);
  transpose_kernel<<<dim3(16, 16), 256, 0, stream>>>(W_v, S->WqkvT + 2 * 512 * 512, 512, 512);
  transpose_kernel<<<dim3(16, 16), 256, 0, stream>>>(W_o, S->WoT, 512, 512);
  transpose_kernel<<<dim3(32, 16), 256, 0, stream>>>(W_m1, S->Wm1T, 512, 1024);
  transpose_kernel<<<dim3(16, 32), 256, 0, stream>>>(W_m2, S->Wm2T, 1024, 512);
  transpose_kernel<<<dim3(16, 32), 256, 0, stream>>>(W_g1, S->Wg1T, 1024, 512);
  transpose_kernel<<<dim3(6, 1024), 256, 0, stream>>>(W_h, S->WhT, 32768, 192);
  memdup_kernel<<<2048, 256, 0, stream>>>(mem_bank, S->memdupB);

  // embedding (writes embh + fused [qh|ql|qh] sim-query rows)
  emb_kernel<<<1024, 256, 0, stream>>>(x_enc, W_val, S->POSb, S->meanv, S->stdv,
                                       S->embh, qsC);
  // retrieval sim: Mtiles=8, nT=64 -> grid 512
  gemm_db<3><<<512, 256, 0, stream>>>(qsC, S->memdupB, nullptr, simB, nullptr, nullptr,
                                      1536, 1536, 1536, 8192, 8192, 64, 0L);
  topk_kernel<<<1024, 256, 0, stream>>>(simB, S->idxB);
  gather_kernel<<<2048, 256, 0, stream>>>(mem_bank, S->idxB, retrB);
  // Wm1: Mtiles=64, nT=8 -> grid 512
  gemm_db<1><<<512, 256, 0, stream>>>(retrB, S->Wm1T, b_m1, hiddenB, nullptr, nullptr,
                                      512, 512, 512, 1024, 1024, 8, 0L);
  gmean_kernel<<<512, 256, 0, stream>>>(hiddenB, S->gmeanB);
  // hmean: Mtiles=8, nT=4 -> grid 32
  gemm_db<0><<<32, 256, 0, stream>>>(S->gmeanB, S->Wm2T, b_m2, S->hmeanB, nullptr, nullptr,
                                     1024, 1024, 1024, 512, 512, 4, 0L);
  // fused QKV: Mtiles=512, nT=12 -> grid 6144
  gemm_db<0><<<6144, 256, 0, stream>>>(S->embh, S->WqkvT, S->bqkv, S->qkvb, nullptr, nullptr,
                                       512, 512, 512, 1536, 1536, 12, 0L);
  // local = emb + hmean -> locglob[:, 0:512]
  local_kernel<<<16384, 256, 0, stream>>>(S->embh, S->hmeanB, S->locglob);
  // attention: O -> contiguous obuf
  attn_kernel<<<dim3(1024, 4), 256, 0, stream>>>(S->qkvb, S->obuf);
  // glob = O @ W_o + b_o -> locglob[:, 512:1024] (contiguous A)
  gemm_db<0><<<2048, 256, 0, stream>>>(S->obuf, S->WoT, b_o, S->locglob + 512, nullptr, nullptr,
                                       512, 512, 512, 512, 1024, 4, 0L);
  // gate logits: single-source K=1024 GEMM + fused gate epilogue
  gemm_db<4><<<2048, 256, 0, stream>>>(S->locglob, S->Wg1T, b_g1, nullptr,
                                       W_g2, S->gatel, 1024, 1024, 1024, 512, 0, 4, 0L);
  // mem = softmax(gate)-combine of locglob halves -> embh
  memc_kernel<<<16384, 256, 0, stream>>>(S->embh, S->locglob, S->gatel, b_g2);
  // mh = mem_flat [1024,32768] @ WhT^T, split-K z=32 (K=1024/slice) -> f32 slices
  // (grid 512 = 2 blocks/CU; was z=16 = 1 block/CU machine-underfill)
  gemm_db<3><<<dim3(16, 1, 32), 256, 0, stream>>>(S->embh, S->WhT, nullptr, mh32,
                                                  nullptr, nullptr,
                                                  32768, 32768, 1024, 192, 192, 2,
                                                  196608L);
  fusion_kernel<<<1024, 256, 0, stream>>>(mh32, b_h, W_f1, b_f1, W_f2, b_f2,
                                          S->meanv, S->stdv, (float*)d_out);
}